// Round 14
// baseline (541.848 us; speedup 1.0000x reference)
//
#include <hip/hip_runtime.h>
#include <hip/hip_bf16.h>

#define HH 768
#define WW 768
#define HWSZ (HH*WW)
#define BN_EPS 1e-5f
#define SEG 8            // conv2 y-band height (power of 2: icorner uses >>3)
#define NSEG 96          // 768 / SEG

typedef __attribute__((ext_vector_type(8))) short bf16x8;
typedef __attribute__((ext_vector_type(4))) float f32x4;

__device__ __forceinline__ float bf2f(unsigned short u) {
  union { unsigned int i; float f; } v; v.i = ((unsigned int)u) << 16; return v.f;
}
__device__ __forceinline__ unsigned short f2bf(float f) {
  union { float f; unsigned int i; } v; v.f = f;
  unsigned int x = v.i;
  return (unsigned short)((x + 0x7fffu + ((x >> 16) & 1u)) >> 16);
}
__device__ __forceinline__ float ldf(const void* p, int i, int flag) {
  return flag ? bf2f(((const unsigned short*)p)[i]) : ((const float*)p)[i];
}

// DPP inclusive prefix over each 16-lane row (pure VALU).
#define DPP_ADD(v, CTRL) do {                                              \
    union { float f; int i; } _u; _u.f = (v);                              \
    int _t = __builtin_amdgcn_update_dpp(0, _u.i, (CTRL), 0xf, 0xf, true); \
    union { int i; float f; } _w; _w.i = _t;                               \
    (v) += _w.f;                                                           \
  } while (0)
__device__ __forceinline__ float row_prefix16(float v) {
  DPP_ADD(v, 0x111);
  DPP_ADD(v, 0x112);
  DPP_ADD(v, 0x114);
  DPP_ADD(v, 0x118);
  return v;
}

__device__ __forceinline__ int detect_flag(const void* v1) {
  const unsigned short* v1raw = (const unsigned short*)v1;
  int ok = 1;
  #pragma unroll
  for (int j = 0; j < 4; ++j) {
    unsigned short u = v1raw[2*j];
    if (u < 0x3E00u || u > 0x4040u) ok = 0;
  }
  return ok;   // 1 = bf16 inputs, 0 = fp32 inputs
}

// ---------------- mega-prep: flag + BN fold + weight reorders + mask build ----------------
// launch: 128 blocks x 256, dynamic LDS = 768*24*4 B (mask scratch, block 127 only)
__global__ void k_prep(const void* __restrict__ c1b,
                       const void* __restrict__ g1, const void* __restrict__ b1,
                       const void* __restrict__ m1, const void* __restrict__ v1,
                       const void* __restrict__ c2b, const void* __restrict__ g2,
                       const void* __restrict__ b2, const void* __restrict__ m2,
                       const void* __restrict__ v2, const void* __restrict__ w1,
                       const void* __restrict__ fb1, const void* __restrict__ fw2,
                       const void* __restrict__ fb2, const void* __restrict__ w2,
                       const void* __restrict__ fw1, const int* __restrict__ boxes,
                       int* __restrict__ flagp, float* __restrict__ cst,
                       unsigned short* __restrict__ A2, unsigned short* __restrict__ A1,
                       unsigned short* __restrict__ w1c, unsigned int* __restrict__ mask)
{
  extern __shared__ unsigned int smask[];
  int flag = detect_flag(v1);
  int tid = threadIdx.x, bid = blockIdx.x;
  int gid = bid * 256 + tid;

  if (bid == 0) {
    if (tid == 0) *flagp = flag;
    float* bias1 = cst + 864;
    float* sc1   = cst + 896;
    float* sh1   = cst + 928;
    float* bias2 = cst + 960;
    float* sc2   = cst + 1024;
    float* sh2   = cst + 1088;
    float* fb1c  = cst + 1152;
    float* w2c   = cst + 1280;
    float* fb2c  = cst + 1792;
    if (tid < 32) {
      float s = ldf(g1, tid, flag) * rsqrtf(ldf(v1, tid, flag) + BN_EPS);
      sc1[tid] = s;
      sh1[tid] = ldf(b1, tid, flag) - ldf(m1, tid, flag) * s;
      bias1[tid] = ldf(c1b, tid, flag);
    }
    if (tid < 64) {
      float s = ldf(g2, tid, flag) * rsqrtf(ldf(v2, tid, flag) + BN_EPS);
      sc2[tid] = s;
      sh2[tid] = ldf(b2, tid, flag) - ldf(m2, tid, flag) * s;
      bias2[tid] = ldf(c2b, tid, flag);
    }
    if (tid < 128) fb1c[tid] = ldf(fb1, tid, flag);
    if (tid < 4)   fb2c[tid] = ldf(fb2, tid, flag);
    for (int i = tid; i < 512; i += 256) w2c[i] = ldf(fw2, i, flag);
  }
  if (bid == 127) {
    // build the T-store corner mask entirely within this block (LDS atomics)
    for (int i = tid; i < 768*24; i += 256) smask[i] = 0u;
    __syncthreads();
    for (int u = tid; u < 512*100; u += 256) {
      int b = u / 100, t = u % 100;
      int a = t / 10, cix = t % 10;
      int xmin = boxes[b*4 + 0], ymin = boxes[b*4 + 1];
      int xmax = boxes[b*4 + 2], ymax = boxes[b*4 + 3];
      int bh = ymax - ymin, bw = xmax - xmin;
      int y = (a < 5) ? (ymin + ((a+1)*bh + 4)/5 - 1) : (ymin + ((a-5)*bh)/5 - 1);
      int x = (cix < 5) ? (xmin + ((cix+1)*bw + 4)/5 - 1) : (xmin + ((cix-5)*bw)/5 - 1);
      if (y >= 0 && x >= 0)
        atomicOr(&smask[y*24 + (x >> 5)], 1u << (x & 31));
    }
    __syncthreads();
    for (int i = tid; i < 768*24; i += 256) mask[i] = smask[i];
  }
  if (gid < 80*288) {
    int o = gid / 288, k = gid % 288, tap = k >> 5, ci = k & 31;
    A2[gid] = (o < 64) ? f2bf(ldf(w2, (o*32 + ci)*9 + tap, flag)) : (unsigned short)0;
  }
  if (gid < 32*64) {
    int o = gid >> 6, k = gid & 63, tap = k >> 2, ci = k & 3;
    A1[gid] = (tap < 9 && ci < 3) ? f2bf(ldf(w1, o*27 + ci*9 + tap, flag))
                                  : (unsigned short)0;
  }
  for (int i = gid; i < 128*1600; i += 128*256) {
    int t = i / 1600, r = i % 1600, cell = r >> 6, c = r & 63;
    w1c[i] = f2bf(ldf(fw1, t*1600 + c*25 + cell, flag));
  }
}

// ---------------- FUSED conv1+conv2+bn+tile-integral -> T NHWC (sparse stores) ----------------
__global__ __launch_bounds__(256) void k_conv12t(const void* __restrict__ img,
    const int* __restrict__ flagp, const unsigned short* __restrict__ A1,
    const unsigned short* __restrict__ A2, const float* __restrict__ cst,
    const unsigned int* __restrict__ mask, float* __restrict__ T)
{
  const float* bias1 = cst + 864;
  const float* sc1   = cst + 896;
  const float* sh1   = cst + 928;
  const float* bias2 = cst + 960;
  const float* sc2   = cst + 1024;
  const float* sh2   = cst + 1088;
  __shared__ unsigned short ftile[10 * 34 * 40];   // feat1 tile, 27,200 B
  __shared__ unsigned short itile[12 * 36 * 4];    // img tile,    3,456 B
  int flag = *flagp;
  int tid = threadIdx.x;
  int xb = blockIdx.x, ys = blockIdx.y;
  int x0 = xb * 32, ybase = ys * SEG;

  for (int idx = tid; idx < 12*36; idx += 256) {
    int r = idx / 36, p = idx % 36;
    int gy = ybase - 2 + r, gx = x0 - 2 + p;
    unsigned short e0 = 0, e1 = 0, e2 = 0;
    if (gy >= 0 && gy < HH && gx >= 0 && gx < WW) {
      e0 = f2bf(ldf(img, 0*HWSZ + gy*WW + gx, flag));
      e1 = f2bf(ldf(img, 1*HWSZ + gy*WW + gx, flag));
      e2 = f2bf(ldf(img, 2*HWSZ + gy*WW + gx, flag));
    }
    ushort4 pk; pk.x = e0; pk.y = e1; pk.z = e2; pk.w = 0;
    *(ushort4*)(itile + idx*4) = pk;
  }

  int w = tid >> 6, lane = tid & 63, quad = lane >> 4, l16 = lane & 15;

  bf16x8 a1f[2][2];
  #pragma unroll
  for (int mt = 0; mt < 2; ++mt)
    #pragma unroll
    for (int kt = 0; kt < 2; ++kt)
      a1f[mt][kt] = *(const bf16x8*)(A1 + (mt*16 + l16)*64 + kt*32 + quad*8);
  int t0 = 2*quad, t1 = 2*quad + 1;
  int ky0 = t0/3, kx0 = t0%3, ky1 = t1/3, kx1 = t1%3;

  int m = w * 16 + l16;
  bf16x8 afrag[9];
  #pragma unroll
  for (int t = 0; t < 9; ++t)
    afrag[t] = *(const bf16x8*)(A2 + m*288 + t*32 + quad*8);
  float bs[4], scv[4], shv[4];
  #pragma unroll
  for (int r = 0; r < 4; ++r) {
    int c = w*16 + quad*4 + r;
    bs[r] = bias2[c]; scv[r] = sc2[c]; shv[r] = sh2[c];
  }
  __syncthreads();   // itile staged

  for (int u = w; u < 30; u += 4) {
    int r = u / 3, nt = u % 3;
    int pxb = nt*16 + l16;
    int pp = (pxb <= 33) ? pxb : 33;
    union { uint2 q[2]; bf16x8 v; } b0;
    b0.q[0] = *(const uint2*)(itile + ((r + ky0)*36 + pp + kx0)*4);
    b0.q[1] = *(const uint2*)(itile + ((r + ky1)*36 + pp + kx1)*4);
    union { uint2 q[2]; bf16x8 v; } b1v;
    b1v.q[0] = *(const uint2*)(itile + ((r + 2)*36 + pp + 2)*4);
    b1v.q[1] = make_uint2(0u, 0u);
    f32x4 acc[2];
    acc[0] = (f32x4){0.f,0.f,0.f,0.f};
    acc[1] = (f32x4){0.f,0.f,0.f,0.f};
    #pragma unroll
    for (int mt = 0; mt < 2; ++mt) {
      acc[mt] = __builtin_amdgcn_mfma_f32_16x16x32_bf16(a1f[mt][0], b0.v, acc[mt], 0, 0, 0);
      acc[mt] = __builtin_amdgcn_mfma_f32_16x16x32_bf16(a1f[mt][1], b1v.v, acc[mt], 0, 0, 0);
    }
    int py = ybase - 1 + r, gx = x0 - 1 + pxb;
    int inside = (py >= 0 && py < HH && gx >= 0 && gx < WW);
    if (pxb < 34) {
      #pragma unroll
      for (int mt = 0; mt < 2; ++mt) {
        int cb = mt*16 + quad*4;
        ushort4 pk;
        if (inside) {
          pk.x = f2bf(fmaxf(acc[mt][0] + bias1[cb+0], 0.f) * sc1[cb+0] + sh1[cb+0]);
          pk.y = f2bf(fmaxf(acc[mt][1] + bias1[cb+1], 0.f) * sc1[cb+1] + sh1[cb+1]);
          pk.z = f2bf(fmaxf(acc[mt][2] + bias1[cb+2], 0.f) * sc1[cb+2] + sh1[cb+2]);
          pk.w = f2bf(fmaxf(acc[mt][3] + bias1[cb+3], 0.f) * sc1[cb+3] + sh1[cb+3]);
        } else {
          pk.x = pk.y = pk.z = pk.w = 0;
        }
        *(ushort4*)(ftile + (r*34 + pxb)*40 + cb) = pk;
      }
    }
  }
  __syncthreads();   // ftile complete; read-only afterwards

  f32x4 ys0 = (f32x4){0.f,0.f,0.f,0.f};
  f32x4 ys1 = (f32x4){0.f,0.f,0.f,0.f};
  int cbase = w*16 + quad*4;
  for (int dy = 0; dy < SEG; ++dy) {
    int y = ybase + dy;
    f32x4 acc[2];
    acc[0] = (f32x4){0.f,0.f,0.f,0.f};
    acc[1] = (f32x4){0.f,0.f,0.f,0.f};
    #pragma unroll
    for (int t = 0; t < 9; ++t) {
      int ky = t / 3, kx = t % 3;
      #pragma unroll
      for (int i = 0; i < 2; ++i) {
        int px = i*16 + l16 + kx;
        bf16x8 b = *(const bf16x8*)(ftile + ((dy + ky)*34 + px)*40 + quad*8);
        acc[i] = __builtin_amdgcn_mfma_f32_16x16x32_bf16(afrag[t], b, acc[i], 0, 0, 0);
      }
    }
    #pragma unroll
    for (int r = 0; r < 4; ++r) {
      float v0 = fmaxf(acc[0][r] + bs[r], 0.f) * scv[r] + shv[r];
      float v1 = fmaxf(acc[1][r] + bs[r], 0.f) * scv[r] + shv[r];
      v0 = row_prefix16(v0);
      v1 = row_prefix16(v1);
      v1 += __shfl(v0, 15, 16);
      ys0[r] += v0;
      ys1[r] += v1;
    }
    unsigned int mw = mask[y*24 + xb];
    int need0 = (dy == SEG-1) || ((mw >> l16) & 1u);
    int need1 = (dy == SEG-1) || (l16 == 15) || ((mw >> (16 + l16)) & 1u);
    if (need0)
      *(f32x4*)(T + ((size_t)(y*WW + x0 + l16))*64 + cbase)      = ys0;
    if (need1)
      *(f32x4*)(T + ((size_t)(y*WW + x0 + 16 + l16))*64 + cbase) = ys1;
  }
}

// ---------------- k_abc: A, B (plain), C — all from T, one launch ----------------
// grid (768, 3): part0 A (768 blocks), part1 B (768), part2 C (first 64 blocks)
__global__ __launch_bounds__(256) void k_abc(const float* __restrict__ T,
    float* __restrict__ A, float* __restrict__ B, float* __restrict__ C)
{
  __shared__ float gtot[4][64];
  __shared__ float Sp[NSEG*24];
  int part = blockIdx.y, tid = threadIdx.x;
  int c = tid & 63, g = tid >> 6;
  if (part == 0) {
    int y = blockIdx.x;
    float vals[6];
    float run = 0.f;
    #pragma unroll
    for (int jj = 0; jj < 6; ++jj) {
      int j = g*6 + jj;
      run += T[((size_t)(y*WW + j*32 + 31))*64 + c];
      vals[jj] = run;
    }
    gtot[g][c] = run;
    __syncthreads();
    float off = 0.f;
    for (int gg = 0; gg < g; ++gg) off += gtot[gg][c];
    #pragma unroll
    for (int jj = 0; jj < 6; ++jj)
      A[((size_t)(y*24 + g*6 + jj))*64 + c] = vals[jj] + off;
  } else if (part == 1) {
    int x = blockIdx.x;
    float vals[24];
    float run = 0.f;
    #pragma unroll 4
    for (int ii = 0; ii < 24; ++ii) {
      int i = g*24 + ii;
      run += T[((size_t)((i*SEG + SEG-1)*WW + x))*64 + c];
      vals[ii] = run;
    }
    gtot[g][c] = run;
    __syncthreads();
    float off = 0.f;
    for (int gg = 0; gg < g; ++gg) off += gtot[gg][c];
    #pragma unroll 4
    for (int ii = 0; ii < 24; ++ii) {
      int i = g*24 + ii;
      B[((size_t)(i*WW + x))*64 + c] = vals[ii] + off;
    }
  } else {
    int cc = blockIdx.x;
    if (cc >= 64) return;
    for (int idx = tid; idx < NSEG*24; idx += 256) {
      int i = idx / 24, j = idx % 24;
      Sp[idx] = T[((size_t)((i*SEG + SEG-1)*WW + j*32 + 31))*64 + cc];
    }
    __syncthreads();
    if (tid < 24) {              // prefix over i
      float run = 0.f;
      for (int i = 0; i < NSEG; ++i) { run += Sp[i*24 + tid]; Sp[i*24 + tid] = run; }
    }
    __syncthreads();
    if (tid < NSEG) {            // prefix over j
      float run = 0.f;
      #pragma unroll
      for (int j = 0; j < 24; ++j) { run += Sp[tid*24 + j]; Sp[tid*24 + j] = run; }
    }
    __syncthreads();
    for (int idx = tid; idx < NSEG*24; idx += 256)
      C[((size_t)idx)*64 + cc] = Sp[idx];
  }
}

// ---------------- 4-term corner (round-5/6 proven decomposition) ----------------
__device__ __forceinline__ float icorner4(const float* __restrict__ T,
    const float* __restrict__ A, const float* __restrict__ B,
    const float* __restrict__ C, int c, int yy, int xx)
{
  int i = yy >> 3, j = xx >> 5;      // SEG == 8
  float v = T[((size_t)(yy*WW + xx))*64 + c];
  if (j > 0) v += A[((size_t)(yy*24 + (j-1)))*64 + c];
  if (i > 0) v += B[((size_t)((i-1)*WW + xx))*64 + c];
  if (i > 0 && j > 0) v += C[((size_t)((i-1)*24 + (j-1)))*64 + c];
  return v;
}

// ---------------- k_roifc: ROI pool -> LDS -> FC1 (MFMA) + relu + FC2 ----------------
// 32 blocks x 16 boxes. Phase 1 writes pooled bf16 straight into the MFMA
// staging buffer (identical values to the old flat round-trip).
__global__ __launch_bounds__(256) void k_roifc(const float* __restrict__ T,
    const float* __restrict__ A, const float* __restrict__ B,
    const float* __restrict__ C, const int* __restrict__ boxes,
    const unsigned short* __restrict__ w1c, const float* __restrict__ cst,
    const int* __restrict__ flagp, void* __restrict__ out)
{
  const float* fb1c = cst + 1152;
  const float* w2c  = cst + 1280;
  const float* fb2c = cst + 1792;
  __shared__ unsigned short sflat[16 * 1608];   // 51,456 B
  __shared__ float hbuf[16 * 132];              //  8,448 B
  int tid = threadIdx.x;
  int b0 = blockIdx.x * 16;

  // ---- phase 1: ROI pooling into sflat ----
  for (int u = tid; u < 16*1600; u += 256) {
    int bi = u / 1600, r = u % 1600;
    int c = r & 63, cell = r >> 6, i = cell / 5, j = cell % 5;
    int bb = b0 + bi;
    int xmin = boxes[bb*4 + 0], ymin = boxes[bb*4 + 1];
    int xmax = boxes[bb*4 + 2], ymax = boxes[bb*4 + 3];
    int bh = ymax - ymin, bw = xmax - xmin;
    int y0 = ymin + (i*bh)/5,  y1 = ymin + ((i+1)*bh + 4)/5;
    int x0 = xmin + (j*bw)/5,  x1 = xmin + ((j+1)*bw + 4)/5;
    float s = icorner4(T, A, B, C, c, y1-1, x1-1);
    if (y0 > 0)           s -= icorner4(T, A, B, C, c, y0-1, x1-1);
    if (x0 > 0)           s -= icorner4(T, A, B, C, c, y1-1, x0-1);
    if (y0 > 0 && x0 > 0) s += icorner4(T, A, B, C, c, y0-1, x0-1);
    float area = (float)((y1 - y0) * (x1 - x0));
    sflat[bi*1608 + cell*64 + c] = f2bf(s / area);
  }
  __syncthreads();

  // ---- phase 2: FC1 MFMA + relu + FC2 (proven k_fcm body) ----
  int w = tid >> 6, lane = tid & 63, quad = lane >> 4, l16 = lane & 15;
  f32x4 acc[2];
  acc[0] = (f32x4){0.f,0.f,0.f,0.f};
  acc[1] = (f32x4){0.f,0.f,0.f,0.f};
  for (int kt = 0; kt < 50; ++kt) {
    bf16x8 b = *(const bf16x8*)(sflat + l16*1608 + kt*32 + quad*8);
    #pragma unroll
    for (int mt = 0; mt < 2; ++mt) {
      bf16x8 a = *(const bf16x8*)(w1c + ((w*2 + mt)*16 + l16)*1600 + kt*32 + quad*8);
      acc[mt] = __builtin_amdgcn_mfma_f32_16x16x32_bf16(a, b, acc[mt], 0, 0, 0);
    }
  }
  #pragma unroll
  for (int mt = 0; mt < 2; ++mt) {
    #pragma unroll
    for (int r = 0; r < 4; ++r) {
      int h = (w*2 + mt)*16 + quad*4 + r;
      hbuf[l16*132 + h] = fmaxf(acc[mt][r] + fb1c[h], 0.f);
    }
  }
  __syncthreads();
  if (tid < 64) {
    int bi = tid >> 2, o = tid & 3;
    float a2 = fb2c[o];
    for (int k = 0; k < 128; ++k) a2 += hbuf[bi*132 + k] * w2c[o*128 + k];
    if (*flagp) ((unsigned short*)out)[(b0 + bi)*4 + o] = f2bf(a2);
    else        ((float*)out)[(b0 + bi)*4 + o] = a2;
  }
}

// ---------------- fallback path (chunked CHW, proven) ----------------
__global__ __launch_bounds__(256) void k_conv1m(const void* __restrict__ img,
    const int* __restrict__ flagp, const unsigned short* __restrict__ A1,
    const float* __restrict__ cst, unsigned short* __restrict__ feat1)
{
  const float* bias1 = cst + 864;
  const float* sc1   = cst + 896;
  const float* sh1   = cst + 928;
  int flag = *flagp;
  __shared__ unsigned short tile[18 * 34 * 4];
  int tid = threadIdx.x;
  int x0 = blockIdx.x * 32, ybase = blockIdx.y * 16;
  for (int idx = tid; idx < 18*34; idx += 256) {
    int r = idx / 34, p = idx % 34;
    int gy = ybase - 1 + r, gx = x0 - 1 + p;
    unsigned short e0 = 0, e1 = 0, e2 = 0;
    if (gy >= 0 && gy < HH && gx >= 0 && gx < WW) {
      e0 = f2bf(ldf(img, 0*HWSZ + gy*WW + gx, flag));
      e1 = f2bf(ldf(img, 1*HWSZ + gy*WW + gx, flag));
      e2 = f2bf(ldf(img, 2*HWSZ + gy*WW + gx, flag));
    }
    ushort4 pk; pk.x = e0; pk.y = e1; pk.z = e2; pk.w = 0;
    *(ushort4*)(tile + idx*4) = pk;
  }
  int w = tid >> 6, lane = tid & 63, quad = lane >> 4, l16 = lane & 15;
  bf16x8 a1f[2][2];
  #pragma unroll
  for (int mt = 0; mt < 2; ++mt)
    #pragma unroll
    for (int kt = 0; kt < 2; ++kt)
      a1f[mt][kt] = *(const bf16x8*)(A1 + (mt*16 + l16)*64 + kt*32 + quad*8);
  int t0 = 2*quad, t1 = 2*quad + 1;
  int ky0 = t0/3, kx0 = t0%3, ky1 = t1/3, kx1 = t1%3;
  __syncthreads();
  for (int dyw = 0; dyw < 4; ++dyw) {
    int dy = dyw*4 + w;
    int y = ybase + dy;
    f32x4 acc[2][2];
    #pragma unroll
    for (int mt = 0; mt < 2; ++mt)
      #pragma unroll
      for (int i = 0; i < 2; ++i)
        acc[mt][i] = (f32x4){0.f,0.f,0.f,0.f};
    #pragma unroll
    for (int i = 0; i < 2; ++i) {
      int pxb = i*16 + l16;
      union { uint2 q[2]; bf16x8 v; } b0;
      b0.q[0] = *(const uint2*)(tile + ((dy + ky0)*34 + pxb + kx0)*4);
      b0.q[1] = *(const uint2*)(tile + ((dy + ky1)*34 + pxb + kx1)*4);
      union { uint2 q[2]; bf16x8 v; } b1v;
      b1v.q[0] = *(const uint2*)(tile + ((dy + 2)*34 + pxb + 2)*4);
      b1v.q[1] = make_uint2(0u, 0u);
      #pragma unroll
      for (int mt = 0; mt < 2; ++mt) {
        acc[mt][i] = __builtin_amdgcn_mfma_f32_16x16x32_bf16(a1f[mt][0], b0.v, acc[mt][i], 0, 0, 0);
        acc[mt][i] = __builtin_amdgcn_mfma_f32_16x16x32_bf16(a1f[mt][1], b1v.v, acc[mt][i], 0, 0, 0);
      }
    }
    #pragma unroll
    for (int mt = 0; mt < 2; ++mt) {
      int cb = mt*16 + quad*4;
      #pragma unroll
      for (int i = 0; i < 2; ++i) {
        int px = x0 + i*16 + l16;
        ushort4 pk;
        pk.x = f2bf(fmaxf(acc[mt][i][0] + bias1[cb+0], 0.f) * sc1[cb+0] + sh1[cb+0]);
        pk.y = f2bf(fmaxf(acc[mt][i][1] + bias1[cb+1], 0.f) * sc1[cb+1] + sh1[cb+1]);
        pk.z = f2bf(fmaxf(acc[mt][i][2] + bias1[cb+2], 0.f) * sc1[cb+2] + sh1[cb+2]);
        pk.w = f2bf(fmaxf(acc[mt][i][3] + bias1[cb+3], 0.f) * sc1[cb+3] + sh1[cb+3]);
        *(ushort4*)(feat1 + ((size_t)(y*WW + px))*32 + cb) = pk;
      }
    }
  }
}
__global__ __launch_bounds__(256) void k_conv2_c16(const unsigned short* __restrict__ feat1,
    const unsigned short* __restrict__ A2, const float* __restrict__ cst,
    float* __restrict__ chunk, int c0, int cnw)
{
  const float* bias2 = cst + 960;
  const float* sc2   = cst + 1024;
  const float* sh2   = cst + 1088;
  __shared__ unsigned short tile[3 * 130 * 40];
  int tid = threadIdx.x;
  int y = blockIdx.y, x0 = blockIdx.x * 128;
  for (int idx = tid; idx < 3*130*4; idx += 256) {
    int q = idx & 3, p = (idx >> 2) % 130, r = idx / 520;
    int gy = y - 1 + r, gx = x0 - 1 + p;
    uint4 val = make_uint4(0u, 0u, 0u, 0u);
    if (gy >= 0 && gy < HH && gx >= 0 && gx < WW)
      val = *(const uint4*)(feat1 + (gy*WW + gx)*32 + q*8);
    *(uint4*)(tile + (r*130 + p)*40 + q*8) = val;
  }
  __syncthreads();
  int w = tid >> 6, lane = tid & 63, quad = lane >> 4, l16 = lane & 15;
  int m = c0 + l16;
  f32x4 acc[2];
  acc[0] = (f32x4){0.f,0.f,0.f,0.f};
  acc[1] = (f32x4){0.f,0.f,0.f,0.f};
  #pragma unroll
  for (int t = 0; t < 9; ++t) {
    int ky = t / 3, kx = t % 3;
    bf16x8 a = *(const bf16x8*)(A2 + m*288 + t*32 + quad*8);
    #pragma unroll
    for (int i = 0; i < 2; ++i) {
      int px = w*32 + i*16 + l16 + kx;
      bf16x8 b = *(const bf16x8*)(tile + (ky*130 + px)*40 + quad*8);
      acc[i] = __builtin_amdgcn_mfma_f32_16x16x32_bf16(a, b, acc[i], 0, 0, 0);
    }
  }
  #pragma unroll
  for (int r = 0; r < 4; ++r) {
    int cl = quad*4 + r;
    if (cl < cnw) {
      int c = c0 + cl;
      float bsv = bias2[c], s = sc2[c], sh = sh2[c];
      float* dst = chunk + cl*HWSZ + y*WW;
      #pragma unroll
      for (int i = 0; i < 2; ++i) {
        float v = fmaxf(acc[i][r] + bsv, 0.f) * s + sh;
        dst[x0 + w*32 + i*16 + l16] = v;
      }
    }
  }
}
__global__ __launch_bounds__(256) void k_csy(float* __restrict__ buf) {
  int t = blockIdx.x * 256 + threadIdx.x;
  int c = t / WW, x = t % WW;
  float* p = buf + c*HWSZ + x;
  float run = 0.f;
  for (int yb = 0; yb < HH; yb += 16) {
    float v[16];
    #pragma unroll
    for (int j = 0; j < 16; ++j) v[j] = p[(yb + j) * WW];
    #pragma unroll
    for (int j = 0; j < 16; ++j) { run += v[j]; v[j] = run; }
    #pragma unroll
    for (int j = 0; j < 16; ++j) p[(yb + j) * WW] = v[j];
  }
}
__global__ __launch_bounds__(256) void k_csx(float* __restrict__ buf) {
  int row = blockIdx.x * 4 + (threadIdx.x >> 6);
  int lane = threadIdx.x & 63;
  float* p = buf + (long)row * WW;
  float carry = 0.f;
  for (int ch = 0; ch < 12; ++ch) {
    float v = p[ch*64 + lane];
    #pragma unroll
    for (int off = 1; off < 64; off <<= 1) {
      float t = __shfl_up(v, off);
      v = (lane >= off) ? v + t : v;
    }
    v += carry;
    p[ch*64 + lane] = v;
    carry = __shfl(v, 63);
  }
}
__global__ __launch_bounds__(256) void k_roi(const float* __restrict__ integ,
    const int* __restrict__ boxes, unsigned short* __restrict__ flat, int c0, int cn)
{
  int b = blockIdx.x;
  int xmin = boxes[b*4 + 0], ymin = boxes[b*4 + 1];
  int xmax = boxes[b*4 + 2], ymax = boxes[b*4 + 3];
  int bh = ymax - ymin, bw = xmax - xmin;
  for (int idx = threadIdx.x; idx < cn*25; idx += 256) {
    int cl = idx / 25, cell = idx % 25, i = cell / 5, j = cell % 5;
    int y0 = ymin + (i*bh)/5,      y1 = ymin + ((i+1)*bh + 4)/5;
    int x0 = xmin + (j*bw)/5,      x1 = xmin + ((j+1)*bw + 4)/5;
    const float* I = integ + cl*HWSZ;
    float a  = I[(y1-1)*WW + (x1-1)];
    float bl = (y0 > 0) ? I[(y0-1)*WW + (x1-1)] : 0.f;
    float cr = (x0 > 0) ? I[(y1-1)*WW + (x0-1)] : 0.f;
    float d  = (y0 > 0 && x0 > 0) ? I[(y0-1)*WW + (x0-1)] : 0.f;
    float s = a - bl - cr + d;
    float area = (float)((y1 - y0) * (x1 - x0));
    flat[b*1600 + cell*64 + (c0 + cl)] = f2bf(s / area);
  }
}
__global__ __launch_bounds__(256) void k_fcm(const unsigned short* __restrict__ flat,
    const unsigned short* __restrict__ w1c, const float* __restrict__ cst,
    const int* __restrict__ flagp, void* __restrict__ out)
{
  const float* fb1c = cst + 1152;
  const float* w2c  = cst + 1280;
  const float* fb2c = cst + 1792;
  __shared__ unsigned short sflat[16 * 1608];
  __shared__ float hbuf[16 * 132];
  int tid = threadIdx.x;
  int b0 = blockIdx.x * 16;
  for (int ii = tid; ii < 3200; ii += 256) {
    int bi = ii / 200, ch = ii % 200;
    *(uint4*)(sflat + bi*1608 + ch*8) = *(const uint4*)(flat + (b0 + bi)*1600 + ch*8);
  }
  __syncthreads();
  int w = tid >> 6, lane = tid & 63, quad = lane >> 4, l16 = lane & 15;
  f32x4 acc[2];
  acc[0] = (f32x4){0.f,0.f,0.f,0.f};
  acc[1] = (f32x4){0.f,0.f,0.f,0.f};
  for (int kt = 0; kt < 50; ++kt) {
    bf16x8 b = *(const bf16x8*)(sflat + l16*1608 + kt*32 + quad*8);
    #pragma unroll
    for (int mt = 0; mt < 2; ++mt) {
      bf16x8 a = *(const bf16x8*)(w1c + ((w*2 + mt)*16 + l16)*1600 + kt*32 + quad*8);
      acc[mt] = __builtin_amdgcn_mfma_f32_16x16x32_bf16(a, b, acc[mt], 0, 0, 0);
    }
  }
  #pragma unroll
  for (int mt = 0; mt < 2; ++mt) {
    #pragma unroll
    for (int r = 0; r < 4; ++r) {
      int h = (w*2 + mt)*16 + quad*4 + r;
      hbuf[l16*132 + h] = fmaxf(acc[mt][r] + fb1c[h], 0.f);
    }
  }
  __syncthreads();
  if (tid < 64) {
    int bi = tid >> 2, o = tid & 3;
    float a2 = fb2c[o];
    for (int k = 0; k < 128; ++k) a2 += hbuf[bi*132 + k] * w2c[o*128 + k];
    if (*flagp) ((unsigned short*)out)[(b0 + bi)*4 + o] = f2bf(a2);
    else        ((float*)out)[(b0 + bi)*4 + o] = a2;
  }
}

extern "C" void kernel_launch(void* const* d_in, const int* in_sizes, int n_in,
                              void* d_out, int out_size, void* d_ws, size_t ws_size,
                              hipStream_t stream) {
  const void* img = d_in[0];
  const int* boxes = (const int*)d_in[1];
  const void* c1w = d_in[2];  const void* c1b = d_in[3];
  const void* g1  = d_in[4];  const void* b1  = d_in[5];
  const void* m1  = d_in[6];  const void* v1  = d_in[7];
  const void* c2w = d_in[8];  const void* c2b = d_in[9];
  const void* g2  = d_in[10]; const void* b2  = d_in[11];
  const void* m2  = d_in[12]; const void* v2  = d_in[13];
  const void* fw1 = d_in[14]; const void* fb1 = d_in[15];
  const void* fw2 = d_in[16]; const void* fb2 = d_in[17];

  // ws layout (same offsets as round 13):
  char* ws = (char*)d_ws;
  unsigned short* A2 = (unsigned short*)ws;
  unsigned short* A1 = (unsigned short*)(ws + 46080);
  float* cst = (float*)(ws + 50176);
  int* flag = (int*)(ws + 57360);
  unsigned int* mask = (unsigned int*)(ws + 57376);
  unsigned short* w1c  = (unsigned short*)(ws + 3592224);
  unsigned short* flat = (unsigned short*)(ws + 4001824);   // fallback only
  unsigned short* feat1 = (unsigned short*)(ws + 7278624);  // fallback only
  float* T = (float*)(ws + 45027360);
  float* Aarr = (float*)(ws + 7278624);
  float* Barr = Aarr + (size_t)768*24*64;
  float* Carr = Barr + (size_t)NSEG*768*64;

  const size_t base = 45027360;
  int cn;
  if      (ws_size >= base + 64ull*HWSZ*4) cn = 64;
  else if (ws_size >= base + 16ull*HWSZ*4) cn = 16;
  else if (ws_size >= base +  8ull*HWSZ*4) cn = 8;
  else if (ws_size >= base +  4ull*HWSZ*4) cn = 4;
  else if (ws_size >= base +  2ull*HWSZ*4) cn = 2;
  else                                     cn = 1;

  hipLaunchKernelGGL(k_prep, dim3(128), dim3(256), 768*24*4, stream,
                     c1b, g1, b1, m1, v1, c2b, g2, b2, m2, v2, c1w,
                     fb1, fw2, fb2, c2w, fw1, boxes, flag, cst, A2, A1, w1c, mask);

  if (cn == 64) {
    hipLaunchKernelGGL(k_conv12t, dim3(24, NSEG), dim3(256), 0, stream,
                       img, flag, A1, A2, cst, mask, T);
    hipLaunchKernelGGL(k_abc, dim3(768, 3), dim3(256), 0, stream,
                       T, Aarr, Barr, Carr);
    hipLaunchKernelGGL(k_roifc, dim3(32), dim3(256), 0, stream,
                       T, Aarr, Barr, Carr, boxes, w1c, cst, flag, d_out);
  } else {
    hipLaunchKernelGGL(k_conv1m, dim3(24, 48), dim3(256), 0, stream,
                       img, flag, A1, cst, feat1);
    for (int c0 = 0; c0 < 64; c0 += cn) {
      hipLaunchKernelGGL(k_conv2_c16, dim3(6, 768), dim3(256), 0, stream,
                         feat1, A2, cst, T, c0, cn);
      hipLaunchKernelGGL(k_csy, dim3(cn*3), dim3(256), 0, stream, T);
      hipLaunchKernelGGL(k_csx, dim3(cn*192), dim3(256), 0, stream, T);
      hipLaunchKernelGGL(k_roi, dim3(512), dim3(256), 0, stream, T, boxes, flat, c0, cn);
    }
    hipLaunchKernelGGL(k_fcm, dim3(32), dim3(256), 0, stream, flat, w1c, cst, flag,
                       d_out);
  }
}

// Round 15
// 258.907 us; speedup vs baseline: 2.0928x; 2.0928x over previous
//
#include <hip/hip_runtime.h>
#include <hip/hip_bf16.h>

#define HH 768
#define WW 768
#define HWSZ (HH*WW)
#define BN_EPS 1e-5f
#define SEG 8            // conv2 y-band height (power of 2: icorner uses >>3)
#define NSEG 96          // 768 / SEG

typedef __attribute__((ext_vector_type(8))) short bf16x8;
typedef __attribute__((ext_vector_type(4))) float f32x4;

__device__ __forceinline__ float bf2f(unsigned short u) {
  union { unsigned int i; float f; } v; v.i = ((unsigned int)u) << 16; return v.f;
}
__device__ __forceinline__ unsigned short f2bf(float f) {
  union { float f; unsigned int i; } v; v.f = f;
  unsigned int x = v.i;
  return (unsigned short)((x + 0x7fffu + ((x >> 16) & 1u)) >> 16);
}
__device__ __forceinline__ float ldf(const void* p, int i, int flag) {
  return flag ? bf2f(((const unsigned short*)p)[i]) : ((const float*)p)[i];
}

// DPP inclusive prefix over each 16-lane row (pure VALU).
#define DPP_ADD(v, CTRL) do {                                              \
    union { float f; int i; } _u; _u.f = (v);                              \
    int _t = __builtin_amdgcn_update_dpp(0, _u.i, (CTRL), 0xf, 0xf, true); \
    union { int i; float f; } _w; _w.i = _t;                               \
    (v) += _w.f;                                                           \
  } while (0)
__device__ __forceinline__ float row_prefix16(float v) {
  DPP_ADD(v, 0x111);
  DPP_ADD(v, 0x112);
  DPP_ADD(v, 0x114);
  DPP_ADD(v, 0x118);
  return v;
}

__device__ __forceinline__ int detect_flag(const void* v1) {
  const unsigned short* v1raw = (const unsigned short*)v1;
  int ok = 1;
  #pragma unroll
  for (int j = 0; j < 4; ++j) {
    unsigned short u = v1raw[2*j];
    if (u < 0x3E00u || u > 0x4040u) ok = 0;
  }
  return ok;   // 1 = bf16 inputs, 0 = fp32 inputs
}

// ---------------- mega-prep: flag + BN fold + weight reorders + mask build ----------------
// launch: 128 blocks x 256, dynamic LDS = 768*24*4 B (mask scratch, block 127 only)
__global__ void k_prep(const void* __restrict__ c1b,
                       const void* __restrict__ g1, const void* __restrict__ b1,
                       const void* __restrict__ m1, const void* __restrict__ v1,
                       const void* __restrict__ c2b, const void* __restrict__ g2,
                       const void* __restrict__ b2, const void* __restrict__ m2,
                       const void* __restrict__ v2, const void* __restrict__ w1,
                       const void* __restrict__ fb1, const void* __restrict__ fw2,
                       const void* __restrict__ fb2, const void* __restrict__ w2,
                       const void* __restrict__ fw1, const int* __restrict__ boxes,
                       int* __restrict__ flagp, float* __restrict__ cst,
                       unsigned short* __restrict__ A2, unsigned short* __restrict__ A1,
                       unsigned short* __restrict__ w1c, unsigned int* __restrict__ mask)
{
  extern __shared__ unsigned int smask[];
  int flag = detect_flag(v1);
  int tid = threadIdx.x, bid = blockIdx.x;
  int gid = bid * 256 + tid;

  if (bid == 0) {
    if (tid == 0) *flagp = flag;
    float* bias1 = cst + 864;
    float* sc1   = cst + 896;
    float* sh1   = cst + 928;
    float* bias2 = cst + 960;
    float* sc2   = cst + 1024;
    float* sh2   = cst + 1088;
    float* fb1c  = cst + 1152;
    float* w2c   = cst + 1280;
    float* fb2c  = cst + 1792;
    if (tid < 32) {
      float s = ldf(g1, tid, flag) * rsqrtf(ldf(v1, tid, flag) + BN_EPS);
      sc1[tid] = s;
      sh1[tid] = ldf(b1, tid, flag) - ldf(m1, tid, flag) * s;
      bias1[tid] = ldf(c1b, tid, flag);
    }
    if (tid < 64) {
      float s = ldf(g2, tid, flag) * rsqrtf(ldf(v2, tid, flag) + BN_EPS);
      sc2[tid] = s;
      sh2[tid] = ldf(b2, tid, flag) - ldf(m2, tid, flag) * s;
      bias2[tid] = ldf(c2b, tid, flag);
    }
    if (tid < 128) fb1c[tid] = ldf(fb1, tid, flag);
    if (tid < 4)   fb2c[tid] = ldf(fb2, tid, flag);
    for (int i = tid; i < 512; i += 256) w2c[i] = ldf(fw2, i, flag);
  }
  if (bid == 127) {
    // build the T-store corner mask entirely within this block (LDS atomics)
    for (int i = tid; i < 768*24; i += 256) smask[i] = 0u;
    __syncthreads();
    for (int u = tid; u < 512*100; u += 256) {
      int b = u / 100, t = u % 100;
      int a = t / 10, cix = t % 10;
      int xmin = boxes[b*4 + 0], ymin = boxes[b*4 + 1];
      int xmax = boxes[b*4 + 2], ymax = boxes[b*4 + 3];
      int bh = ymax - ymin, bw = xmax - xmin;
      int y = (a < 5) ? (ymin + ((a+1)*bh + 4)/5 - 1) : (ymin + ((a-5)*bh)/5 - 1);
      int x = (cix < 5) ? (xmin + ((cix+1)*bw + 4)/5 - 1) : (xmin + ((cix-5)*bw)/5 - 1);
      if (y >= 0 && x >= 0)
        atomicOr(&smask[y*24 + (x >> 5)], 1u << (x & 31));
    }
    __syncthreads();
    for (int i = tid; i < 768*24; i += 256) mask[i] = smask[i];
  }
  if (gid < 80*288) {
    int o = gid / 288, k = gid % 288, tap = k >> 5, ci = k & 31;
    A2[gid] = (o < 64) ? f2bf(ldf(w2, (o*32 + ci)*9 + tap, flag)) : (unsigned short)0;
  }
  if (gid < 32*64) {
    int o = gid >> 6, k = gid & 63, tap = k >> 2, ci = k & 3;
    A1[gid] = (tap < 9 && ci < 3) ? f2bf(ldf(w1, o*27 + ci*9 + tap, flag))
                                  : (unsigned short)0;
  }
  for (int i = gid; i < 128*1600; i += 128*256) {
    int t = i / 1600, r = i % 1600, cell = r >> 6, c = r & 63;
    w1c[i] = f2bf(ldf(fw1, t*1600 + c*25 + cell, flag));
  }
}

// ---------------- FUSED conv1+conv2+bn+tile-integral -> T NHWC (sparse stores) ----------------
__global__ __launch_bounds__(256) void k_conv12t(const void* __restrict__ img,
    const int* __restrict__ flagp, const unsigned short* __restrict__ A1,
    const unsigned short* __restrict__ A2, const float* __restrict__ cst,
    const unsigned int* __restrict__ mask, float* __restrict__ T)
{
  const float* bias1 = cst + 864;
  const float* sc1   = cst + 896;
  const float* sh1   = cst + 928;
  const float* bias2 = cst + 960;
  const float* sc2   = cst + 1024;
  const float* sh2   = cst + 1088;
  __shared__ unsigned short ftile[10 * 34 * 40];   // feat1 tile, 27,200 B
  __shared__ unsigned short itile[12 * 36 * 4];    // img tile,    3,456 B
  int flag = *flagp;
  int tid = threadIdx.x;
  int xb = blockIdx.x, ys = blockIdx.y;
  int x0 = xb * 32, ybase = ys * SEG;

  for (int idx = tid; idx < 12*36; idx += 256) {
    int r = idx / 36, p = idx % 36;
    int gy = ybase - 2 + r, gx = x0 - 2 + p;
    unsigned short e0 = 0, e1 = 0, e2 = 0;
    if (gy >= 0 && gy < HH && gx >= 0 && gx < WW) {
      e0 = f2bf(ldf(img, 0*HWSZ + gy*WW + gx, flag));
      e1 = f2bf(ldf(img, 1*HWSZ + gy*WW + gx, flag));
      e2 = f2bf(ldf(img, 2*HWSZ + gy*WW + gx, flag));
    }
    ushort4 pk; pk.x = e0; pk.y = e1; pk.z = e2; pk.w = 0;
    *(ushort4*)(itile + idx*4) = pk;
  }

  int w = tid >> 6, lane = tid & 63, quad = lane >> 4, l16 = lane & 15;

  bf16x8 a1f[2][2];
  #pragma unroll
  for (int mt = 0; mt < 2; ++mt)
    #pragma unroll
    for (int kt = 0; kt < 2; ++kt)
      a1f[mt][kt] = *(const bf16x8*)(A1 + (mt*16 + l16)*64 + kt*32 + quad*8);
  int t0 = 2*quad, t1 = 2*quad + 1;
  int ky0 = t0/3, kx0 = t0%3, ky1 = t1/3, kx1 = t1%3;

  int m = w * 16 + l16;
  bf16x8 afrag[9];
  #pragma unroll
  for (int t = 0; t < 9; ++t)
    afrag[t] = *(const bf16x8*)(A2 + m*288 + t*32 + quad*8);
  float bs[4], scv[4], shv[4];
  #pragma unroll
  for (int r = 0; r < 4; ++r) {
    int c = w*16 + quad*4 + r;
    bs[r] = bias2[c]; scv[r] = sc2[c]; shv[r] = sh2[c];
  }
  __syncthreads();   // itile staged

  for (int u = w; u < 30; u += 4) {
    int r = u / 3, nt = u % 3;
    int pxb = nt*16 + l16;
    int pp = (pxb <= 33) ? pxb : 33;
    union { uint2 q[2]; bf16x8 v; } b0;
    b0.q[0] = *(const uint2*)(itile + ((r + ky0)*36 + pp + kx0)*4);
    b0.q[1] = *(const uint2*)(itile + ((r + ky1)*36 + pp + kx1)*4);
    union { uint2 q[2]; bf16x8 v; } b1v;
    b1v.q[0] = *(const uint2*)(itile + ((r + 2)*36 + pp + 2)*4);
    b1v.q[1] = make_uint2(0u, 0u);
    f32x4 acc[2];
    acc[0] = (f32x4){0.f,0.f,0.f,0.f};
    acc[1] = (f32x4){0.f,0.f,0.f,0.f};
    #pragma unroll
    for (int mt = 0; mt < 2; ++mt) {
      acc[mt] = __builtin_amdgcn_mfma_f32_16x16x32_bf16(a1f[mt][0], b0.v, acc[mt], 0, 0, 0);
      acc[mt] = __builtin_amdgcn_mfma_f32_16x16x32_bf16(a1f[mt][1], b1v.v, acc[mt], 0, 0, 0);
    }
    int py = ybase - 1 + r, gx = x0 - 1 + pxb;
    int inside = (py >= 0 && py < HH && gx >= 0 && gx < WW);
    if (pxb < 34) {
      #pragma unroll
      for (int mt = 0; mt < 2; ++mt) {
        int cb = mt*16 + quad*4;
        ushort4 pk;
        if (inside) {
          pk.x = f2bf(fmaxf(acc[mt][0] + bias1[cb+0], 0.f) * sc1[cb+0] + sh1[cb+0]);
          pk.y = f2bf(fmaxf(acc[mt][1] + bias1[cb+1], 0.f) * sc1[cb+1] + sh1[cb+1]);
          pk.z = f2bf(fmaxf(acc[mt][2] + bias1[cb+2], 0.f) * sc1[cb+2] + sh1[cb+2]);
          pk.w = f2bf(fmaxf(acc[mt][3] + bias1[cb+3], 0.f) * sc1[cb+3] + sh1[cb+3]);
        } else {
          pk.x = pk.y = pk.z = pk.w = 0;
        }
        *(ushort4*)(ftile + (r*34 + pxb)*40 + cb) = pk;
      }
    }
  }
  __syncthreads();   // ftile complete; read-only afterwards

  f32x4 ys0 = (f32x4){0.f,0.f,0.f,0.f};
  f32x4 ys1 = (f32x4){0.f,0.f,0.f,0.f};
  int cbase = w*16 + quad*4;
  for (int dy = 0; dy < SEG; ++dy) {
    int y = ybase + dy;
    f32x4 acc[2];
    acc[0] = (f32x4){0.f,0.f,0.f,0.f};
    acc[1] = (f32x4){0.f,0.f,0.f,0.f};
    #pragma unroll
    for (int t = 0; t < 9; ++t) {
      int ky = t / 3, kx = t % 3;
      #pragma unroll
      for (int i = 0; i < 2; ++i) {
        int px = i*16 + l16 + kx;
        bf16x8 b = *(const bf16x8*)(ftile + ((dy + ky)*34 + px)*40 + quad*8);
        acc[i] = __builtin_amdgcn_mfma_f32_16x16x32_bf16(afrag[t], b, acc[i], 0, 0, 0);
      }
    }
    #pragma unroll
    for (int r = 0; r < 4; ++r) {
      float v0 = fmaxf(acc[0][r] + bs[r], 0.f) * scv[r] + shv[r];
      float v1 = fmaxf(acc[1][r] + bs[r], 0.f) * scv[r] + shv[r];
      v0 = row_prefix16(v0);
      v1 = row_prefix16(v1);
      v1 += __shfl(v0, 15, 16);
      ys0[r] += v0;
      ys1[r] += v1;
    }
    unsigned int mw = mask[y*24 + xb];
    int need0 = (dy == SEG-1) || ((mw >> l16) & 1u);
    int need1 = (dy == SEG-1) || (l16 == 15) || ((mw >> (16 + l16)) & 1u);
    if (need0)
      *(f32x4*)(T + ((size_t)(y*WW + x0 + l16))*64 + cbase)      = ys0;
    if (need1)
      *(f32x4*)(T + ((size_t)(y*WW + x0 + 16 + l16))*64 + cbase) = ys1;
  }
}

// ---------------- k_abc: A, B (plain), C — all from T, one launch ----------------
// grid (768, 3): part0 A (768 blocks), part1 B (768), part2 C (first 64 blocks)
__global__ __launch_bounds__(256) void k_abc(const float* __restrict__ T,
    float* __restrict__ A, float* __restrict__ B, float* __restrict__ C)
{
  __shared__ float gtot[4][64];
  __shared__ float Sp[NSEG*24];
  int part = blockIdx.y, tid = threadIdx.x;
  int c = tid & 63, g = tid >> 6;
  if (part == 0) {
    int y = blockIdx.x;
    float vals[6];
    float run = 0.f;
    #pragma unroll
    for (int jj = 0; jj < 6; ++jj) {
      int j = g*6 + jj;
      run += T[((size_t)(y*WW + j*32 + 31))*64 + c];
      vals[jj] = run;
    }
    gtot[g][c] = run;
    __syncthreads();
    float off = 0.f;
    for (int gg = 0; gg < g; ++gg) off += gtot[gg][c];
    #pragma unroll
    for (int jj = 0; jj < 6; ++jj)
      A[((size_t)(y*24 + g*6 + jj))*64 + c] = vals[jj] + off;
  } else if (part == 1) {
    int x = blockIdx.x;
    float vals[24];
    float run = 0.f;
    #pragma unroll 4
    for (int ii = 0; ii < 24; ++ii) {
      int i = g*24 + ii;
      run += T[((size_t)((i*SEG + SEG-1)*WW + x))*64 + c];
      vals[ii] = run;
    }
    gtot[g][c] = run;
    __syncthreads();
    float off = 0.f;
    for (int gg = 0; gg < g; ++gg) off += gtot[gg][c];
    #pragma unroll 4
    for (int ii = 0; ii < 24; ++ii) {
      int i = g*24 + ii;
      B[((size_t)(i*WW + x))*64 + c] = vals[ii] + off;
    }
  } else {
    int cc = blockIdx.x;
    if (cc >= 64) return;
    for (int idx = tid; idx < NSEG*24; idx += 256) {
      int i = idx / 24, j = idx % 24;
      Sp[idx] = T[((size_t)((i*SEG + SEG-1)*WW + j*32 + 31))*64 + cc];
    }
    __syncthreads();
    if (tid < 24) {              // prefix over i
      float run = 0.f;
      for (int i = 0; i < NSEG; ++i) { run += Sp[i*24 + tid]; Sp[i*24 + tid] = run; }
    }
    __syncthreads();
    if (tid < NSEG) {            // prefix over j
      float run = 0.f;
      #pragma unroll
      for (int j = 0; j < 24; ++j) { run += Sp[tid*24 + j]; Sp[tid*24 + j] = run; }
    }
    __syncthreads();
    for (int idx = tid; idx < NSEG*24; idx += 256)
      C[((size_t)idx)*64 + cc] = Sp[idx];
  }
}

// ---------------- 4-term corner (numerics proven in R14 phase 1) ----------------
__device__ __forceinline__ float icorner4(const float* __restrict__ T,
    const float* __restrict__ A, const float* __restrict__ B,
    const float* __restrict__ C, int c, int yy, int xx)
{
  int i = yy >> 3, j = xx >> 5;      // SEG == 8
  float v = T[((size_t)(yy*WW + xx))*64 + c];
  if (j > 0) v += A[((size_t)(yy*24 + (j-1)))*64 + c];
  if (i > 0) v += B[((size_t)((i-1)*WW + xx))*64 + c];
  if (i > 0 && j > 0) v += C[((size_t)((i-1)*24 + (j-1)))*64 + c];
  return v;
}

// ---------------- ROI pool (512 blocks — full gather TLP) -> flat bf16 ----------------
__global__ __launch_bounds__(256) void k_roi3(const float* __restrict__ T,
    const float* __restrict__ A, const float* __restrict__ B,
    const float* __restrict__ C, const int* __restrict__ boxes,
    unsigned short* __restrict__ flat)
{
  int b = blockIdx.x;
  int xmin = boxes[b*4 + 0], ymin = boxes[b*4 + 1];
  int xmax = boxes[b*4 + 2], ymax = boxes[b*4 + 3];
  int bh = ymax - ymin, bw = xmax - xmin;
  for (int idx = threadIdx.x; idx < 1600; idx += 256) {
    int c = idx & 63, cell = idx >> 6, i = cell / 5, j = cell % 5;
    int y0 = ymin + (i*bh)/5,  y1 = ymin + ((i+1)*bh + 4)/5;
    int x0 = xmin + (j*bw)/5,  x1 = xmin + ((j+1)*bw + 4)/5;
    float s = icorner4(T, A, B, C, c, y1-1, x1-1);
    if (y0 > 0)           s -= icorner4(T, A, B, C, c, y0-1, x1-1);
    if (x0 > 0)           s -= icorner4(T, A, B, C, c, y1-1, x0-1);
    if (y0 > 0 && x0 > 0) s += icorner4(T, A, B, C, c, y0-1, x0-1);
    float area = (float)((y1 - y0) * (x1 - x0));
    flat[b*1600 + cell*64 + c] = f2bf(s / area);
  }
}

// ---------------- FC1 (MFMA) + relu + FC2, 16 boxes/block ----------------
__global__ __launch_bounds__(256) void k_fcm(const unsigned short* __restrict__ flat,
    const unsigned short* __restrict__ w1c, const float* __restrict__ cst,
    const int* __restrict__ flagp, void* __restrict__ out)
{
  const float* fb1c = cst + 1152;
  const float* w2c  = cst + 1280;
  const float* fb2c = cst + 1792;
  __shared__ unsigned short sflat[16 * 1608];
  __shared__ float hbuf[16 * 132];
  int tid = threadIdx.x;
  int b0 = blockIdx.x * 16;
  for (int ii = tid; ii < 3200; ii += 256) {
    int bi = ii / 200, ch = ii % 200;
    *(uint4*)(sflat + bi*1608 + ch*8) = *(const uint4*)(flat + (b0 + bi)*1600 + ch*8);
  }
  __syncthreads();
  int w = tid >> 6, lane = tid & 63, quad = lane >> 4, l16 = lane & 15;
  f32x4 acc[2];
  acc[0] = (f32x4){0.f,0.f,0.f,0.f};
  acc[1] = (f32x4){0.f,0.f,0.f,0.f};
  for (int kt = 0; kt < 50; ++kt) {
    bf16x8 b = *(const bf16x8*)(sflat + l16*1608 + kt*32 + quad*8);
    #pragma unroll
    for (int mt = 0; mt < 2; ++mt) {
      bf16x8 a = *(const bf16x8*)(w1c + ((w*2 + mt)*16 + l16)*1600 + kt*32 + quad*8);
      acc[mt] = __builtin_amdgcn_mfma_f32_16x16x32_bf16(a, b, acc[mt], 0, 0, 0);
    }
  }
  #pragma unroll
  for (int mt = 0; mt < 2; ++mt) {
    #pragma unroll
    for (int r = 0; r < 4; ++r) {
      int h = (w*2 + mt)*16 + quad*4 + r;
      hbuf[l16*132 + h] = fmaxf(acc[mt][r] + fb1c[h], 0.f);
    }
  }
  __syncthreads();
  if (tid < 64) {
    int bi = tid >> 2, o = tid & 3;
    float a2 = fb2c[o];
    for (int k = 0; k < 128; ++k) a2 += hbuf[bi*132 + k] * w2c[o*128 + k];
    if (*flagp) ((unsigned short*)out)[(b0 + bi)*4 + o] = f2bf(a2);
    else        ((float*)out)[(b0 + bi)*4 + o] = a2;
  }
}

// ---------------- fallback path (chunked CHW, proven) ----------------
__global__ __launch_bounds__(256) void k_conv1m(const void* __restrict__ img,
    const int* __restrict__ flagp, const unsigned short* __restrict__ A1,
    const float* __restrict__ cst, unsigned short* __restrict__ feat1)
{
  const float* bias1 = cst + 864;
  const float* sc1   = cst + 896;
  const float* sh1   = cst + 928;
  int flag = *flagp;
  __shared__ unsigned short tile[18 * 34 * 4];
  int tid = threadIdx.x;
  int x0 = blockIdx.x * 32, ybase = blockIdx.y * 16;
  for (int idx = tid; idx < 18*34; idx += 256) {
    int r = idx / 34, p = idx % 34;
    int gy = ybase - 1 + r, gx = x0 - 1 + p;
    unsigned short e0 = 0, e1 = 0, e2 = 0;
    if (gy >= 0 && gy < HH && gx >= 0 && gx < WW) {
      e0 = f2bf(ldf(img, 0*HWSZ + gy*WW + gx, flag));
      e1 = f2bf(ldf(img, 1*HWSZ + gy*WW + gx, flag));
      e2 = f2bf(ldf(img, 2*HWSZ + gy*WW + gx, flag));
    }
    ushort4 pk; pk.x = e0; pk.y = e1; pk.z = e2; pk.w = 0;
    *(ushort4*)(tile + idx*4) = pk;
  }
  int w = tid >> 6, lane = tid & 63, quad = lane >> 4, l16 = lane & 15;
  bf16x8 a1f[2][2];
  #pragma unroll
  for (int mt = 0; mt < 2; ++mt)
    #pragma unroll
    for (int kt = 0; kt < 2; ++kt)
      a1f[mt][kt] = *(const bf16x8*)(A1 + (mt*16 + l16)*64 + kt*32 + quad*8);
  int t0 = 2*quad, t1 = 2*quad + 1;
  int ky0 = t0/3, kx0 = t0%3, ky1 = t1/3, kx1 = t1%3;
  __syncthreads();
  for (int dyw = 0; dyw < 4; ++dyw) {
    int dy = dyw*4 + w;
    int y = ybase + dy;
    f32x4 acc[2][2];
    #pragma unroll
    for (int mt = 0; mt < 2; ++mt)
      #pragma unroll
      for (int i = 0; i < 2; ++i)
        acc[mt][i] = (f32x4){0.f,0.f,0.f,0.f};
    #pragma unroll
    for (int i = 0; i < 2; ++i) {
      int pxb = i*16 + l16;
      union { uint2 q[2]; bf16x8 v; } b0;
      b0.q[0] = *(const uint2*)(tile + ((dy + ky0)*34 + pxb + kx0)*4);
      b0.q[1] = *(const uint2*)(tile + ((dy + ky1)*34 + pxb + kx1)*4);
      union { uint2 q[2]; bf16x8 v; } b1v;
      b1v.q[0] = *(const uint2*)(tile + ((dy + 2)*34 + pxb + 2)*4);
      b1v.q[1] = make_uint2(0u, 0u);
      #pragma unroll
      for (int mt = 0; mt < 2; ++mt) {
        acc[mt][i] = __builtin_amdgcn_mfma_f32_16x16x32_bf16(a1f[mt][0], b0.v, acc[mt][i], 0, 0, 0);
        acc[mt][i] = __builtin_amdgcn_mfma_f32_16x16x32_bf16(a1f[mt][1], b1v.v, acc[mt][i], 0, 0, 0);
      }
    }
    #pragma unroll
    for (int mt = 0; mt < 2; ++mt) {
      int cb = mt*16 + quad*4;
      #pragma unroll
      for (int i = 0; i < 2; ++i) {
        int px = x0 + i*16 + l16;
        ushort4 pk;
        pk.x = f2bf(fmaxf(acc[mt][i][0] + bias1[cb+0], 0.f) * sc1[cb+0] + sh1[cb+0]);
        pk.y = f2bf(fmaxf(acc[mt][i][1] + bias1[cb+1], 0.f) * sc1[cb+1] + sh1[cb+1]);
        pk.z = f2bf(fmaxf(acc[mt][i][2] + bias1[cb+2], 0.f) * sc1[cb+2] + sh1[cb+2]);
        pk.w = f2bf(fmaxf(acc[mt][i][3] + bias1[cb+3], 0.f) * sc1[cb+3] + sh1[cb+3]);
        *(ushort4*)(feat1 + ((size_t)(y*WW + px))*32 + cb) = pk;
      }
    }
  }
}
__global__ __launch_bounds__(256) void k_conv2_c16(const unsigned short* __restrict__ feat1,
    const unsigned short* __restrict__ A2, const float* __restrict__ cst,
    float* __restrict__ chunk, int c0, int cnw)
{
  const float* bias2 = cst + 960;
  const float* sc2   = cst + 1024;
  const float* sh2   = cst + 1088;
  __shared__ unsigned short tile[3 * 130 * 40];
  int tid = threadIdx.x;
  int y = blockIdx.y, x0 = blockIdx.x * 128;
  for (int idx = tid; idx < 3*130*4; idx += 256) {
    int q = idx & 3, p = (idx >> 2) % 130, r = idx / 520;
    int gy = y - 1 + r, gx = x0 - 1 + p;
    uint4 val = make_uint4(0u, 0u, 0u, 0u);
    if (gy >= 0 && gy < HH && gx >= 0 && gx < WW)
      val = *(const uint4*)(feat1 + (gy*WW + gx)*32 + q*8);
    *(uint4*)(tile + (r*130 + p)*40 + q*8) = val;
  }
  __syncthreads();
  int w = tid >> 6, lane = tid & 63, quad = lane >> 4, l16 = lane & 15;
  int m = c0 + l16;
  f32x4 acc[2];
  acc[0] = (f32x4){0.f,0.f,0.f,0.f};
  acc[1] = (f32x4){0.f,0.f,0.f,0.f};
  #pragma unroll
  for (int t = 0; t < 9; ++t) {
    int ky = t / 3, kx = t % 3;
    bf16x8 a = *(const bf16x8*)(A2 + m*288 + t*32 + quad*8);
    #pragma unroll
    for (int i = 0; i < 2; ++i) {
      int px = w*32 + i*16 + l16 + kx;
      bf16x8 b = *(const bf16x8*)(tile + (ky*130 + px)*40 + quad*8);
      acc[i] = __builtin_amdgcn_mfma_f32_16x16x32_bf16(a, b, acc[i], 0, 0, 0);
    }
  }
  #pragma unroll
  for (int r = 0; r < 4; ++r) {
    int cl = quad*4 + r;
    if (cl < cnw) {
      int c = c0 + cl;
      float bsv = bias2[c], s = sc2[c], sh = sh2[c];
      float* dst = chunk + cl*HWSZ + y*WW;
      #pragma unroll
      for (int i = 0; i < 2; ++i) {
        float v = fmaxf(acc[i][r] + bsv, 0.f) * s + sh;
        dst[x0 + w*32 + i*16 + l16] = v;
      }
    }
  }
}
__global__ __launch_bounds__(256) void k_csy(float* __restrict__ buf) {
  int t = blockIdx.x * 256 + threadIdx.x;
  int c = t / WW, x = t % WW;
  float* p = buf + c*HWSZ + x;
  float run = 0.f;
  for (int yb = 0; yb < HH; yb += 16) {
    float v[16];
    #pragma unroll
    for (int j = 0; j < 16; ++j) v[j] = p[(yb + j) * WW];
    #pragma unroll
    for (int j = 0; j < 16; ++j) { run += v[j]; v[j] = run; }
    #pragma unroll
    for (int j = 0; j < 16; ++j) p[(yb + j) * WW] = v[j];
  }
}
__global__ __launch_bounds__(256) void k_csx(float* __restrict__ buf) {
  int row = blockIdx.x * 4 + (threadIdx.x >> 6);
  int lane = threadIdx.x & 63;
  float* p = buf + (long)row * WW;
  float carry = 0.f;
  for (int ch = 0; ch < 12; ++ch) {
    float v = p[ch*64 + lane];
    #pragma unroll
    for (int off = 1; off < 64; off <<= 1) {
      float t = __shfl_up(v, off);
      v = (lane >= off) ? v + t : v;
    }
    v += carry;
    p[ch*64 + lane] = v;
    carry = __shfl(v, 63);
  }
}
__global__ __launch_bounds__(256) void k_roi(const float* __restrict__ integ,
    const int* __restrict__ boxes, unsigned short* __restrict__ flat, int c0, int cn)
{
  int b = blockIdx.x;
  int xmin = boxes[b*4 + 0], ymin = boxes[b*4 + 1];
  int xmax = boxes[b*4 + 2], ymax = boxes[b*4 + 3];
  int bh = ymax - ymin, bw = xmax - xmin;
  for (int idx = threadIdx.x; idx < cn*25; idx += 256) {
    int cl = idx / 25, cell = idx % 25, i = cell / 5, j = cell % 5;
    int y0 = ymin + (i*bh)/5,      y1 = ymin + ((i+1)*bh + 4)/5;
    int x0 = xmin + (j*bw)/5,      x1 = xmin + ((j+1)*bw + 4)/5;
    const float* I = integ + cl*HWSZ;
    float a  = I[(y1-1)*WW + (x1-1)];
    float bl = (y0 > 0) ? I[(y0-1)*WW + (x1-1)] : 0.f;
    float cr = (x0 > 0) ? I[(y1-1)*WW + (x0-1)] : 0.f;
    float d  = (y0 > 0 && x0 > 0) ? I[(y0-1)*WW + (x0-1)] : 0.f;
    float s = a - bl - cr + d;
    float area = (float)((y1 - y0) * (x1 - x0));
    flat[b*1600 + cell*64 + (c0 + cl)] = f2bf(s / area);
  }
}

extern "C" void kernel_launch(void* const* d_in, const int* in_sizes, int n_in,
                              void* d_out, int out_size, void* d_ws, size_t ws_size,
                              hipStream_t stream) {
  const void* img = d_in[0];
  const int* boxes = (const int*)d_in[1];
  const void* c1w = d_in[2];  const void* c1b = d_in[3];
  const void* g1  = d_in[4];  const void* b1  = d_in[5];
  const void* m1  = d_in[6];  const void* v1  = d_in[7];
  const void* c2w = d_in[8];  const void* c2b = d_in[9];
  const void* g2  = d_in[10]; const void* b2  = d_in[11];
  const void* m2  = d_in[12]; const void* v2  = d_in[13];
  const void* fw1 = d_in[14]; const void* fb1 = d_in[15];
  const void* fw2 = d_in[16]; const void* fb2 = d_in[17];

  // ws layout (same offsets as round 13/14):
  char* ws = (char*)d_ws;
  unsigned short* A2 = (unsigned short*)ws;
  unsigned short* A1 = (unsigned short*)(ws + 46080);
  float* cst = (float*)(ws + 50176);
  int* flag = (int*)(ws + 57360);
  unsigned int* mask = (unsigned int*)(ws + 57376);
  unsigned short* w1c  = (unsigned short*)(ws + 3592224);
  unsigned short* flat = (unsigned short*)(ws + 4001824);
  unsigned short* feat1 = (unsigned short*)(ws + 7278624);  // fallback only
  float* T = (float*)(ws + 45027360);
  float* Aarr = (float*)(ws + 7278624);
  float* Barr = Aarr + (size_t)768*24*64;
  float* Carr = Barr + (size_t)NSEG*768*64;

  const size_t base = 45027360;
  int cn;
  if      (ws_size >= base + 64ull*HWSZ*4) cn = 64;
  else if (ws_size >= base + 16ull*HWSZ*4) cn = 16;
  else if (ws_size >= base +  8ull*HWSZ*4) cn = 8;
  else if (ws_size >= base +  4ull*HWSZ*4) cn = 4;
  else if (ws_size >= base +  2ull*HWSZ*4) cn = 2;
  else                                     cn = 1;

  hipLaunchKernelGGL(k_prep, dim3(128), dim3(256), 768*24*4, stream,
                     c1b, g1, b1, m1, v1, c2b, g2, b2, m2, v2, c1w,
                     fb1, fw2, fb2, c2w, fw1, boxes, flag, cst, A2, A1, w1c, mask);

  if (cn == 64) {
    hipLaunchKernelGGL(k_conv12t, dim3(24, NSEG), dim3(256), 0, stream,
                       img, flag, A1, A2, cst, mask, T);
    hipLaunchKernelGGL(k_abc, dim3(768, 3), dim3(256), 0, stream,
                       T, Aarr, Barr, Carr);
    hipLaunchKernelGGL(k_roi3, dim3(512), dim3(256), 0, stream,
                       T, Aarr, Barr, Carr, boxes, flat);
    hipLaunchKernelGGL(k_fcm, dim3(32), dim3(256), 0, stream, flat, w1c, cst, flag,
                       d_out);
  } else {
    hipLaunchKernelGGL(k_conv1m, dim3(24, 48), dim3(256), 0, stream,
                       img, flag, A1, cst, feat1);
    for (int c0 = 0; c0 < 64; c0 += cn) {
      hipLaunchKernelGGL(k_conv2_c16, dim3(6, 768), dim3(256), 0, stream,
                         feat1, A2, cst, T, c0, cn);
      hipLaunchKernelGGL(k_csy, dim3(cn*3), dim3(256), 0, stream, T);
      hipLaunchKernelGGL(k_csx, dim3(cn*192), dim3(256), 0, stream, T);
      hipLaunchKernelGGL(k_roi, dim3(512), dim3(256), 0, stream, T, boxes, flat, c0, cn);
    }
    hipLaunchKernelGGL(k_fcm, dim3(32), dim3(256), 0, stream, flat, w1c, cst, flag,
                       d_out);
  }
}

// Round 16
// 206.529 us; speedup vs baseline: 2.6236x; 1.2536x over previous
//
#include <hip/hip_runtime.h>
#include <hip/hip_bf16.h>

#define HH 768
#define WW 768
#define HWSZ (HH*WW)
#define BN_EPS 1e-5f
#define SEG 8            // conv2 y-band height (power of 2: icorner uses >>3)
#define NSEG 96          // 768 / SEG

typedef __attribute__((ext_vector_type(8))) short bf16x8;
typedef __attribute__((ext_vector_type(4))) float f32x4;

__device__ __forceinline__ float bf2f(unsigned short u) {
  union { unsigned int i; float f; } v; v.i = ((unsigned int)u) << 16; return v.f;
}
__device__ __forceinline__ unsigned short f2bf(float f) {
  union { float f; unsigned int i; } v; v.f = f;
  unsigned int x = v.i;
  return (unsigned short)((x + 0x7fffu + ((x >> 16) & 1u)) >> 16);
}
__device__ __forceinline__ float ldf(const void* p, int i, int flag) {
  return flag ? bf2f(((const unsigned short*)p)[i]) : ((const float*)p)[i];
}

// DPP inclusive prefix over each 16-lane row (pure VALU).
#define DPP_ADD(v, CTRL) do {                                              \
    union { float f; int i; } _u; _u.f = (v);                              \
    int _t = __builtin_amdgcn_update_dpp(0, _u.i, (CTRL), 0xf, 0xf, true); \
    union { int i; float f; } _w; _w.i = _t;                               \
    (v) += _w.f;                                                           \
  } while (0)
__device__ __forceinline__ float row_prefix16(float v) {
  DPP_ADD(v, 0x111);
  DPP_ADD(v, 0x112);
  DPP_ADD(v, 0x114);
  DPP_ADD(v, 0x118);
  return v;
}

__device__ __forceinline__ int detect_flag(const void* v1) {
  const unsigned short* v1raw = (const unsigned short*)v1;
  int ok = 1;
  #pragma unroll
  for (int j = 0; j < 4; ++j) {
    unsigned short u = v1raw[2*j];
    if (u < 0x3E00u || u > 0x4040u) ok = 0;
  }
  return ok;   // 1 = bf16 inputs, 0 = fp32 inputs
}

// ---------------- mega-prep: flag + BN fold + weight reorders + mask zero ----------------
// grid 256 x 256; no mask build here (single-block serialization proved a 45 us tail)
__global__ void k_prep(const void* __restrict__ c1b,
                       const void* __restrict__ g1, const void* __restrict__ b1,
                       const void* __restrict__ m1, const void* __restrict__ v1,
                       const void* __restrict__ c2b, const void* __restrict__ g2,
                       const void* __restrict__ b2, const void* __restrict__ m2,
                       const void* __restrict__ v2, const void* __restrict__ w1,
                       const void* __restrict__ fb1, const void* __restrict__ fw2,
                       const void* __restrict__ fb2, const void* __restrict__ w2,
                       const void* __restrict__ fw1,
                       int* __restrict__ flagp, float* __restrict__ cst,
                       unsigned short* __restrict__ A2, unsigned short* __restrict__ A1,
                       unsigned short* __restrict__ w1c, unsigned int* __restrict__ mask)
{
  int flag = detect_flag(v1);
  int tid = threadIdx.x, bid = blockIdx.x;
  int gid = bid * 256 + tid;

  // zero the T-store mask (768*24 words); k_mask (next launch) sets bits
  if (gid < 768*24) mask[gid] = 0u;

  if (bid == 0) {
    if (tid == 0) *flagp = flag;
    float* bias1 = cst + 864;
    float* sc1   = cst + 896;
    float* sh1   = cst + 928;
    float* bias2 = cst + 960;
    float* sc2   = cst + 1024;
    float* sh2   = cst + 1088;
    float* fb1c  = cst + 1152;
    float* w2c   = cst + 1280;
    float* fb2c  = cst + 1792;
    if (tid < 32) {
      float s = ldf(g1, tid, flag) * rsqrtf(ldf(v1, tid, flag) + BN_EPS);
      sc1[tid] = s;
      sh1[tid] = ldf(b1, tid, flag) - ldf(m1, tid, flag) * s;
      bias1[tid] = ldf(c1b, tid, flag);
    }
    if (tid < 64) {
      float s = ldf(g2, tid, flag) * rsqrtf(ldf(v2, tid, flag) + BN_EPS);
      sc2[tid] = s;
      sh2[tid] = ldf(b2, tid, flag) - ldf(m2, tid, flag) * s;
      bias2[tid] = ldf(c2b, tid, flag);
    }
    if (tid < 128) fb1c[tid] = ldf(fb1, tid, flag);
    if (tid < 4)   fb2c[tid] = ldf(fb2, tid, flag);
    for (int i = tid; i < 512; i += 256) w2c[i] = ldf(fw2, i, flag);
  }
  if (gid < 80*288) {
    int o = gid / 288, k = gid % 288, tap = k >> 5, ci = k & 31;
    A2[gid] = (o < 64) ? f2bf(ldf(w2, (o*32 + ci)*9 + tap, flag)) : (unsigned short)0;
  }
  if (gid < 32*64) {
    int o = gid >> 6, k = gid & 63, tap = k >> 2, ci = k & 3;
    A1[gid] = (tap < 9 && ci < 3) ? f2bf(ldf(w1, o*27 + ci*9 + tap, flag))
                                  : (unsigned short)0;
  }
  // fc1_w -> bf16 permuted: COALESCED reads (consecutive src), scattered writes
  for (int s = gid; s < 128*1600; s += 256*256) {
    int t = s / 1600, r = s % 1600, c = r / 25, cell = r % 25;
    w1c[t*1600 + cell*64 + c] = f2bf(ldf(fw1, s, flag));
  }
}

// ---------------- k_mask: set corner bits from boxes (512 blocks — proven fast) ----------------
__global__ __launch_bounds__(128) void k_mask(const int* __restrict__ boxes,
                                              unsigned int* __restrict__ mask)
{
  int b = blockIdx.x, t = threadIdx.x;
  if (t >= 100) return;
  int a = t / 10, cix = t % 10;
  int xmin = boxes[b*4 + 0], ymin = boxes[b*4 + 1];
  int xmax = boxes[b*4 + 2], ymax = boxes[b*4 + 3];
  int bh = ymax - ymin, bw = xmax - xmin;
  int y, x;
  if (a < 5) y = ymin + ((a+1)*bh + 4)/5 - 1;   // y1[i]-1
  else       y = ymin + ((a-5)*bh)/5 - 1;       // y0[i]-1
  if (cix < 5) x = xmin + ((cix+1)*bw + 4)/5 - 1;
  else         x = xmin + ((cix-5)*bw)/5 - 1;
  if (y >= 0 && x >= 0)
    atomicOr(&mask[y*24 + (x >> 5)], 1u << (x & 31));
}

// ---------------- FUSED conv1+conv2+bn+tile-integral -> T NHWC (sparse stores) ----------------
__global__ __launch_bounds__(256) void k_conv12t(const void* __restrict__ img,
    const int* __restrict__ flagp, const unsigned short* __restrict__ A1,
    const unsigned short* __restrict__ A2, const float* __restrict__ cst,
    const unsigned int* __restrict__ mask, float* __restrict__ T)
{
  const float* bias1 = cst + 864;
  const float* sc1   = cst + 896;
  const float* sh1   = cst + 928;
  const float* bias2 = cst + 960;
  const float* sc2   = cst + 1024;
  const float* sh2   = cst + 1088;
  __shared__ unsigned short ftile[10 * 34 * 40];   // feat1 tile, 27,200 B
  __shared__ unsigned short itile[12 * 36 * 4];    // img tile,    3,456 B
  int flag = *flagp;
  int tid = threadIdx.x;
  int xb = blockIdx.x, ys = blockIdx.y;
  int x0 = xb * 32, ybase = ys * SEG;

  for (int idx = tid; idx < 12*36; idx += 256) {
    int r = idx / 36, p = idx % 36;
    int gy = ybase - 2 + r, gx = x0 - 2 + p;
    unsigned short e0 = 0, e1 = 0, e2 = 0;
    if (gy >= 0 && gy < HH && gx >= 0 && gx < WW) {
      e0 = f2bf(ldf(img, 0*HWSZ + gy*WW + gx, flag));
      e1 = f2bf(ldf(img, 1*HWSZ + gy*WW + gx, flag));
      e2 = f2bf(ldf(img, 2*HWSZ + gy*WW + gx, flag));
    }
    ushort4 pk; pk.x = e0; pk.y = e1; pk.z = e2; pk.w = 0;
    *(ushort4*)(itile + idx*4) = pk;
  }

  int w = tid >> 6, lane = tid & 63, quad = lane >> 4, l16 = lane & 15;

  bf16x8 a1f[2][2];
  #pragma unroll
  for (int mt = 0; mt < 2; ++mt)
    #pragma unroll
    for (int kt = 0; kt < 2; ++kt)
      a1f[mt][kt] = *(const bf16x8*)(A1 + (mt*16 + l16)*64 + kt*32 + quad*8);
  int t0 = 2*quad, t1 = 2*quad + 1;
  int ky0 = t0/3, kx0 = t0%3, ky1 = t1/3, kx1 = t1%3;

  int m = w * 16 + l16;
  bf16x8 afrag[9];
  #pragma unroll
  for (int t = 0; t < 9; ++t)
    afrag[t] = *(const bf16x8*)(A2 + m*288 + t*32 + quad*8);
  float bs[4], scv[4], shv[4];
  #pragma unroll
  for (int r = 0; r < 4; ++r) {
    int c = w*16 + quad*4 + r;
    bs[r] = bias2[c]; scv[r] = sc2[c]; shv[r] = sh2[c];
  }
  __syncthreads();   // itile staged

  for (int u = w; u < 30; u += 4) {
    int r = u / 3, nt = u % 3;
    int pxb = nt*16 + l16;
    int pp = (pxb <= 33) ? pxb : 33;
    union { uint2 q[2]; bf16x8 v; } b0;
    b0.q[0] = *(const uint2*)(itile + ((r + ky0)*36 + pp + kx0)*4);
    b0.q[1] = *(const uint2*)(itile + ((r + ky1)*36 + pp + kx1)*4);
    union { uint2 q[2]; bf16x8 v; } b1v;
    b1v.q[0] = *(const uint2*)(itile + ((r + 2)*36 + pp + 2)*4);
    b1v.q[1] = make_uint2(0u, 0u);
    f32x4 acc[2];
    acc[0] = (f32x4){0.f,0.f,0.f,0.f};
    acc[1] = (f32x4){0.f,0.f,0.f,0.f};
    #pragma unroll
    for (int mt = 0; mt < 2; ++mt) {
      acc[mt] = __builtin_amdgcn_mfma_f32_16x16x32_bf16(a1f[mt][0], b0.v, acc[mt], 0, 0, 0);
      acc[mt] = __builtin_amdgcn_mfma_f32_16x16x32_bf16(a1f[mt][1], b1v.v, acc[mt], 0, 0, 0);
    }
    int py = ybase - 1 + r, gx = x0 - 1 + pxb;
    int inside = (py >= 0 && py < HH && gx >= 0 && gx < WW);
    if (pxb < 34) {
      #pragma unroll
      for (int mt = 0; mt < 2; ++mt) {
        int cb = mt*16 + quad*4;
        ushort4 pk;
        if (inside) {
          pk.x = f2bf(fmaxf(acc[mt][0] + bias1[cb+0], 0.f) * sc1[cb+0] + sh1[cb+0]);
          pk.y = f2bf(fmaxf(acc[mt][1] + bias1[cb+1], 0.f) * sc1[cb+1] + sh1[cb+1]);
          pk.z = f2bf(fmaxf(acc[mt][2] + bias1[cb+2], 0.f) * sc1[cb+2] + sh1[cb+2]);
          pk.w = f2bf(fmaxf(acc[mt][3] + bias1[cb+3], 0.f) * sc1[cb+3] + sh1[cb+3]);
        } else {
          pk.x = pk.y = pk.z = pk.w = 0;
        }
        *(ushort4*)(ftile + (r*34 + pxb)*40 + cb) = pk;
      }
    }
  }
  __syncthreads();   // ftile complete; read-only afterwards

  f32x4 ys0 = (f32x4){0.f,0.f,0.f,0.f};
  f32x4 ys1 = (f32x4){0.f,0.f,0.f,0.f};
  int cbase = w*16 + quad*4;
  for (int dy = 0; dy < SEG; ++dy) {
    int y = ybase + dy;
    f32x4 acc[2];
    acc[0] = (f32x4){0.f,0.f,0.f,0.f};
    acc[1] = (f32x4){0.f,0.f,0.f,0.f};
    #pragma unroll
    for (int t = 0; t < 9; ++t) {
      int ky = t / 3, kx = t % 3;
      #pragma unroll
      for (int i = 0; i < 2; ++i) {
        int px = i*16 + l16 + kx;
        bf16x8 b = *(const bf16x8*)(ftile + ((dy + ky)*34 + px)*40 + quad*8);
        acc[i] = __builtin_amdgcn_mfma_f32_16x16x32_bf16(afrag[t], b, acc[i], 0, 0, 0);
      }
    }
    #pragma unroll
    for (int r = 0; r < 4; ++r) {
      float v0 = fmaxf(acc[0][r] + bs[r], 0.f) * scv[r] + shv[r];
      float v1 = fmaxf(acc[1][r] + bs[r], 0.f) * scv[r] + shv[r];
      v0 = row_prefix16(v0);
      v1 = row_prefix16(v1);
      v1 += __shfl(v0, 15, 16);
      ys0[r] += v0;
      ys1[r] += v1;
    }
    unsigned int mw = mask[y*24 + xb];
    int need0 = (dy == SEG-1) || ((mw >> l16) & 1u);
    int need1 = (dy == SEG-1) || (l16 == 15) || ((mw >> (16 + l16)) & 1u);
    if (need0)
      *(f32x4*)(T + ((size_t)(y*WW + x0 + l16))*64 + cbase)      = ys0;
    if (need1)
      *(f32x4*)(T + ((size_t)(y*WW + x0 + 16 + l16))*64 + cbase) = ys1;
  }
}

// ---------------- k_abc: A, B (plain), C — all from T, one launch ----------------
__global__ __launch_bounds__(256) void k_abc(const float* __restrict__ T,
    float* __restrict__ A, float* __restrict__ B, float* __restrict__ C)
{
  __shared__ float gtot[4][64];
  __shared__ float Sp[NSEG*24];
  int part = blockIdx.y, tid = threadIdx.x;
  int c = tid & 63, g = tid >> 6;
  if (part == 0) {
    int y = blockIdx.x;
    float vals[6];
    float run = 0.f;
    #pragma unroll
    for (int jj = 0; jj < 6; ++jj) {
      int j = g*6 + jj;
      run += T[((size_t)(y*WW + j*32 + 31))*64 + c];
      vals[jj] = run;
    }
    gtot[g][c] = run;
    __syncthreads();
    float off = 0.f;
    for (int gg = 0; gg < g; ++gg) off += gtot[gg][c];
    #pragma unroll
    for (int jj = 0; jj < 6; ++jj)
      A[((size_t)(y*24 + g*6 + jj))*64 + c] = vals[jj] + off;
  } else if (part == 1) {
    int x = blockIdx.x;
    float vals[24];
    float run = 0.f;
    #pragma unroll 4
    for (int ii = 0; ii < 24; ++ii) {
      int i = g*24 + ii;
      run += T[((size_t)((i*SEG + SEG-1)*WW + x))*64 + c];
      vals[ii] = run;
    }
    gtot[g][c] = run;
    __syncthreads();
    float off = 0.f;
    for (int gg = 0; gg < g; ++gg) off += gtot[gg][c];
    #pragma unroll 4
    for (int ii = 0; ii < 24; ++ii) {
      int i = g*24 + ii;
      B[((size_t)(i*WW + x))*64 + c] = vals[ii] + off;
    }
  } else {
    int cc = blockIdx.x;
    if (cc >= 64) return;
    for (int idx = tid; idx < NSEG*24; idx += 256) {
      int i = idx / 24, j = idx % 24;
      Sp[idx] = T[((size_t)((i*SEG + SEG-1)*WW + j*32 + 31))*64 + cc];
    }
    __syncthreads();
    if (tid < 24) {              // prefix over i
      float run = 0.f;
      for (int i = 0; i < NSEG; ++i) { run += Sp[i*24 + tid]; Sp[i*24 + tid] = run; }
    }
    __syncthreads();
    if (tid < NSEG) {            // prefix over j
      float run = 0.f;
      #pragma unroll
      for (int j = 0; j < 24; ++j) { run += Sp[tid*24 + j]; Sp[tid*24 + j] = run; }
    }
    __syncthreads();
    for (int idx = tid; idx < NSEG*24; idx += 256)
      C[((size_t)idx)*64 + cc] = Sp[idx];
  }
}

// ---------------- 4-term corner ----------------
__device__ __forceinline__ float icorner4(const float* __restrict__ T,
    const float* __restrict__ A, const float* __restrict__ B,
    const float* __restrict__ C, int c, int yy, int xx)
{
  int i = yy >> 3, j = xx >> 5;      // SEG == 8
  float v = T[((size_t)(yy*WW + xx))*64 + c];
  if (j > 0) v += A[((size_t)(yy*24 + (j-1)))*64 + c];
  if (i > 0) v += B[((size_t)((i-1)*WW + xx))*64 + c];
  if (i > 0 && j > 0) v += C[((size_t)((i-1)*24 + (j-1)))*64 + c];
  return v;
}

// ---------------- ROI pool (512 blocks — full gather TLP) -> flat bf16 ----------------
__global__ __launch_bounds__(256) void k_roi3(const float* __restrict__ T,
    const float* __restrict__ A, const float* __restrict__ B,
    const float* __restrict__ C, const int* __restrict__ boxes,
    unsigned short* __restrict__ flat)
{
  int b = blockIdx.x;
  int xmin = boxes[b*4 + 0], ymin = boxes[b*4 + 1];
  int xmax = boxes[b*4 + 2], ymax = boxes[b*4 + 3];
  int bh = ymax - ymin, bw = xmax - xmin;
  for (int idx = threadIdx.x; idx < 1600; idx += 256) {
    int c = idx & 63, cell = idx >> 6, i = cell / 5, j = cell % 5;
    int y0 = ymin + (i*bh)/5,  y1 = ymin + ((i+1)*bh + 4)/5;
    int x0 = xmin + (j*bw)/5,  x1 = xmin + ((j+1)*bw + 4)/5;
    float s = icorner4(T, A, B, C, c, y1-1, x1-1);
    if (y0 > 0)           s -= icorner4(T, A, B, C, c, y0-1, x1-1);
    if (x0 > 0)           s -= icorner4(T, A, B, C, c, y1-1, x0-1);
    if (y0 > 0 && x0 > 0) s += icorner4(T, A, B, C, c, y0-1, x0-1);
    float area = (float)((y1 - y0) * (x1 - x0));
    flat[b*1600 + cell*64 + c] = f2bf(s / area);
  }
}

// ---------------- FC1 (MFMA) + relu + FC2, 16 boxes/block ----------------
__global__ __launch_bounds__(256) void k_fcm(const unsigned short* __restrict__ flat,
    const unsigned short* __restrict__ w1c, const float* __restrict__ cst,
    const int* __restrict__ flagp, void* __restrict__ out)
{
  const float* fb1c = cst + 1152;
  const float* w2c  = cst + 1280;
  const float* fb2c = cst + 1792;
  __shared__ unsigned short sflat[16 * 1608];
  __shared__ float hbuf[16 * 132];
  int tid = threadIdx.x;
  int b0 = blockIdx.x * 16;
  for (int ii = tid; ii < 3200; ii += 256) {
    int bi = ii / 200, ch = ii % 200;
    *(uint4*)(sflat + bi*1608 + ch*8) = *(const uint4*)(flat + (b0 + bi)*1600 + ch*8);
  }
  __syncthreads();
  int w = tid >> 6, lane = tid & 63, quad = lane >> 4, l16 = lane & 15;
  f32x4 acc[2];
  acc[0] = (f32x4){0.f,0.f,0.f,0.f};
  acc[1] = (f32x4){0.f,0.f,0.f,0.f};
  for (int kt = 0; kt < 50; ++kt) {
    bf16x8 b = *(const bf16x8*)(sflat + l16*1608 + kt*32 + quad*8);
    #pragma unroll
    for (int mt = 0; mt < 2; ++mt) {
      bf16x8 a = *(const bf16x8*)(w1c + ((w*2 + mt)*16 + l16)*1600 + kt*32 + quad*8);
      acc[mt] = __builtin_amdgcn_mfma_f32_16x16x32_bf16(a, b, acc[mt], 0, 0, 0);
    }
  }
  #pragma unroll
  for (int mt = 0; mt < 2; ++mt) {
    #pragma unroll
    for (int r = 0; r < 4; ++r) {
      int h = (w*2 + mt)*16 + quad*4 + r;
      hbuf[l16*132 + h] = fmaxf(acc[mt][r] + fb1c[h], 0.f);
    }
  }
  __syncthreads();
  if (tid < 64) {
    int bi = tid >> 2, o = tid & 3;
    float a2 = fb2c[o];
    for (int k = 0; k < 128; ++k) a2 += hbuf[bi*132 + k] * w2c[o*128 + k];
    if (*flagp) ((unsigned short*)out)[(b0 + bi)*4 + o] = f2bf(a2);
    else        ((float*)out)[(b0 + bi)*4 + o] = a2;
  }
}

// ---------------- fallback path (chunked CHW, proven) ----------------
__global__ __launch_bounds__(256) void k_conv1m(const void* __restrict__ img,
    const int* __restrict__ flagp, const unsigned short* __restrict__ A1,
    const float* __restrict__ cst, unsigned short* __restrict__ feat1)
{
  const float* bias1 = cst + 864;
  const float* sc1   = cst + 896;
  const float* sh1   = cst + 928;
  int flag = *flagp;
  __shared__ unsigned short tile[18 * 34 * 4];
  int tid = threadIdx.x;
  int x0 = blockIdx.x * 32, ybase = blockIdx.y * 16;
  for (int idx = tid; idx < 18*34; idx += 256) {
    int r = idx / 34, p = idx % 34;
    int gy = ybase - 1 + r, gx = x0 - 1 + p;
    unsigned short e0 = 0, e1 = 0, e2 = 0;
    if (gy >= 0 && gy < HH && gx >= 0 && gx < WW) {
      e0 = f2bf(ldf(img, 0*HWSZ + gy*WW + gx, flag));
      e1 = f2bf(ldf(img, 1*HWSZ + gy*WW + gx, flag));
      e2 = f2bf(ldf(img, 2*HWSZ + gy*WW + gx, flag));
    }
    ushort4 pk; pk.x = e0; pk.y = e1; pk.z = e2; pk.w = 0;
    *(ushort4*)(tile + idx*4) = pk;
  }
  int w = tid >> 6, lane = tid & 63, quad = lane >> 4, l16 = lane & 15;
  bf16x8 a1f[2][2];
  #pragma unroll
  for (int mt = 0; mt < 2; ++mt)
    #pragma unroll
    for (int kt = 0; kt < 2; ++kt)
      a1f[mt][kt] = *(const bf16x8*)(A1 + (mt*16 + l16)*64 + kt*32 + quad*8);
  int t0 = 2*quad, t1 = 2*quad + 1;
  int ky0 = t0/3, kx0 = t0%3, ky1 = t1/3, kx1 = t1%3;
  __syncthreads();
  for (int dyw = 0; dyw < 4; ++dyw) {
    int dy = dyw*4 + w;
    int y = ybase + dy;
    f32x4 acc[2][2];
    #pragma unroll
    for (int mt = 0; mt < 2; ++mt)
      #pragma unroll
      for (int i = 0; i < 2; ++i)
        acc[mt][i] = (f32x4){0.f,0.f,0.f,0.f};
    #pragma unroll
    for (int i = 0; i < 2; ++i) {
      int pxb = i*16 + l16;
      union { uint2 q[2]; bf16x8 v; } b0;
      b0.q[0] = *(const uint2*)(tile + ((dy + ky0)*34 + pxb + kx0)*4);
      b0.q[1] = *(const uint2*)(tile + ((dy + ky1)*34 + pxb + kx1)*4);
      union { uint2 q[2]; bf16x8 v; } b1v;
      b1v.q[0] = *(const uint2*)(tile + ((dy + 2)*34 + pxb + 2)*4);
      b1v.q[1] = make_uint2(0u, 0u);
      #pragma unroll
      for (int mt = 0; mt < 2; ++mt) {
        acc[mt][i] = __builtin_amdgcn_mfma_f32_16x16x32_bf16(a1f[mt][0], b0.v, acc[mt][i], 0, 0, 0);
        acc[mt][i] = __builtin_amdgcn_mfma_f32_16x16x32_bf16(a1f[mt][1], b1v.v, acc[mt][i], 0, 0, 0);
      }
    }
    #pragma unroll
    for (int mt = 0; mt < 2; ++mt) {
      int cb = mt*16 + quad*4;
      #pragma unroll
      for (int i = 0; i < 2; ++i) {
        int px = x0 + i*16 + l16;
        ushort4 pk;
        pk.x = f2bf(fmaxf(acc[mt][i][0] + bias1[cb+0], 0.f) * sc1[cb+0] + sh1[cb+0]);
        pk.y = f2bf(fmaxf(acc[mt][i][1] + bias1[cb+1], 0.f) * sc1[cb+1] + sh1[cb+1]);
        pk.z = f2bf(fmaxf(acc[mt][i][2] + bias1[cb+2], 0.f) * sc1[cb+2] + sh1[cb+2]);
        pk.w = f2bf(fmaxf(acc[mt][i][3] + bias1[cb+3], 0.f) * sc1[cb+3] + sh1[cb+3]);
        *(ushort4*)(feat1 + ((size_t)(y*WW + px))*32 + cb) = pk;
      }
    }
  }
}
__global__ __launch_bounds__(256) void k_conv2_c16(const unsigned short* __restrict__ feat1,
    const unsigned short* __restrict__ A2, const float* __restrict__ cst,
    float* __restrict__ chunk, int c0, int cnw)
{
  const float* bias2 = cst + 960;
  const float* sc2   = cst + 1024;
  const float* sh2   = cst + 1088;
  __shared__ unsigned short tile[3 * 130 * 40];
  int tid = threadIdx.x;
  int y = blockIdx.y, x0 = blockIdx.x * 128;
  for (int idx = tid; idx < 3*130*4; idx += 256) {
    int q = idx & 3, p = (idx >> 2) % 130, r = idx / 520;
    int gy = y - 1 + r, gx = x0 - 1 + p;
    uint4 val = make_uint4(0u, 0u, 0u, 0u);
    if (gy >= 0 && gy < HH && gx >= 0 && gx < WW)
      val = *(const uint4*)(feat1 + (gy*WW + gx)*32 + q*8);
    *(uint4*)(tile + (r*130 + p)*40 + q*8) = val;
  }
  __syncthreads();
  int w = tid >> 6, lane = tid & 63, quad = lane >> 4, l16 = lane & 15;
  int m = c0 + l16;
  f32x4 acc[2];
  acc[0] = (f32x4){0.f,0.f,0.f,0.f};
  acc[1] = (f32x4){0.f,0.f,0.f,0.f};
  #pragma unroll
  for (int t = 0; t < 9; ++t) {
    int ky = t / 3, kx = t % 3;
    bf16x8 a = *(const bf16x8*)(A2 + m*288 + t*32 + quad*8);
    #pragma unroll
    for (int i = 0; i < 2; ++i) {
      int px = w*32 + i*16 + l16 + kx;
      bf16x8 b = *(const bf16x8*)(tile + (ky*130 + px)*40 + quad*8);
      acc[i] = __builtin_amdgcn_mfma_f32_16x16x32_bf16(a, b, acc[i], 0, 0, 0);
    }
  }
  #pragma unroll
  for (int r = 0; r < 4; ++r) {
    int cl = quad*4 + r;
    if (cl < cnw) {
      int c = c0 + cl;
      float bsv = bias2[c], s = sc2[c], sh = sh2[c];
      float* dst = chunk + cl*HWSZ + y*WW;
      #pragma unroll
      for (int i = 0; i < 2; ++i) {
        float v = fmaxf(acc[i][r] + bsv, 0.f) * s + sh;
        dst[x0 + w*32 + i*16 + l16] = v;
      }
    }
  }
}
__global__ __launch_bounds__(256) void k_csy(float* __restrict__ buf) {
  int t = blockIdx.x * 256 + threadIdx.x;
  int c = t / WW, x = t % WW;
  float* p = buf + c*HWSZ + x;
  float run = 0.f;
  for (int yb = 0; yb < HH; yb += 16) {
    float v[16];
    #pragma unroll
    for (int j = 0; j < 16; ++j) v[j] = p[(yb + j) * WW];
    #pragma unroll
    for (int j = 0; j < 16; ++j) { run += v[j]; v[j] = run; }
    #pragma unroll
    for (int j = 0; j < 16; ++j) p[(yb + j) * WW] = v[j];
  }
}
__global__ __launch_bounds__(256) void k_csx(float* __restrict__ buf) {
  int row = blockIdx.x * 4 + (threadIdx.x >> 6);
  int lane = threadIdx.x & 63;
  float* p = buf + (long)row * WW;
  float carry = 0.f;
  for (int ch = 0; ch < 12; ++ch) {
    float v = p[ch*64 + lane];
    #pragma unroll
    for (int off = 1; off < 64; off <<= 1) {
      float t = __shfl_up(v, off);
      v = (lane >= off) ? v + t : v;
    }
    v += carry;
    p[ch*64 + lane] = v;
    carry = __shfl(v, 63);
  }
}
__global__ __launch_bounds__(256) void k_roi(const float* __restrict__ integ,
    const int* __restrict__ boxes, unsigned short* __restrict__ flat, int c0, int cn)
{
  int b = blockIdx.x;
  int xmin = boxes[b*4 + 0], ymin = boxes[b*4 + 1];
  int xmax = boxes[b*4 + 2], ymax = boxes[b*4 + 3];
  int bh = ymax - ymin, bw = xmax - xmin;
  for (int idx = threadIdx.x; idx < cn*25; idx += 256) {
    int cl = idx / 25, cell = idx % 25, i = cell / 5, j = cell % 5;
    int y0 = ymin + (i*bh)/5,      y1 = ymin + ((i+1)*bh + 4)/5;
    int x0 = xmin + (j*bw)/5,      x1 = xmin + ((j+1)*bw + 4)/5;
    const float* I = integ + cl*HWSZ;
    float a  = I[(y1-1)*WW + (x1-1)];
    float bl = (y0 > 0) ? I[(y0-1)*WW + (x1-1)] : 0.f;
    float cr = (x0 > 0) ? I[(y1-1)*WW + (x0-1)] : 0.f;
    float d  = (y0 > 0 && x0 > 0) ? I[(y0-1)*WW + (x0-1)] : 0.f;
    float s = a - bl - cr + d;
    float area = (float)((y1 - y0) * (x1 - x0));
    flat[b*1600 + cell*64 + (c0 + cl)] = f2bf(s / area);
  }
}

extern "C" void kernel_launch(void* const* d_in, const int* in_sizes, int n_in,
                              void* d_out, int out_size, void* d_ws, size_t ws_size,
                              hipStream_t stream) {
  const void* img = d_in[0];
  const int* boxes = (const int*)d_in[1];
  const void* c1w = d_in[2];  const void* c1b = d_in[3];
  const void* g1  = d_in[4];  const void* b1  = d_in[5];
  const void* m1  = d_in[6];  const void* v1  = d_in[7];
  const void* c2w = d_in[8];  const void* c2b = d_in[9];
  const void* g2  = d_in[10]; const void* b2  = d_in[11];
  const void* m2  = d_in[12]; const void* v2  = d_in[13];
  const void* fw1 = d_in[14]; const void* fb1 = d_in[15];
  const void* fw2 = d_in[16]; const void* fb2 = d_in[17];

  // ws layout (same offsets as rounds 13-15):
  char* ws = (char*)d_ws;
  unsigned short* A2 = (unsigned short*)ws;
  unsigned short* A1 = (unsigned short*)(ws + 46080);
  float* cst = (float*)(ws + 50176);
  int* flag = (int*)(ws + 57360);
  unsigned int* mask = (unsigned int*)(ws + 57376);
  unsigned short* w1c  = (unsigned short*)(ws + 3592224);
  unsigned short* flat = (unsigned short*)(ws + 4001824);
  unsigned short* feat1 = (unsigned short*)(ws + 7278624);  // fallback only
  float* T = (float*)(ws + 45027360);
  float* Aarr = (float*)(ws + 7278624);
  float* Barr = Aarr + (size_t)768*24*64;
  float* Carr = Barr + (size_t)NSEG*768*64;

  const size_t base = 45027360;
  int cn;
  if      (ws_size >= base + 64ull*HWSZ*4) cn = 64;
  else if (ws_size >= base + 16ull*HWSZ*4) cn = 16;
  else if (ws_size >= base +  8ull*HWSZ*4) cn = 8;
  else if (ws_size >= base +  4ull*HWSZ*4) cn = 4;
  else if (ws_size >= base +  2ull*HWSZ*4) cn = 2;
  else                                     cn = 1;

  hipLaunchKernelGGL(k_prep, dim3(256), dim3(256), 0, stream,
                     c1b, g1, b1, m1, v1, c2b, g2, b2, m2, v2, c1w,
                     fb1, fw2, fb2, c2w, fw1, flag, cst, A2, A1, w1c, mask);

  if (cn == 64) {
    hipLaunchKernelGGL(k_mask, dim3(512), dim3(128), 0, stream, boxes, mask);
    hipLaunchKernelGGL(k_conv12t, dim3(24, NSEG), dim3(256), 0, stream,
                       img, flag, A1, A2, cst, mask, T);
    hipLaunchKernelGGL(k_abc, dim3(768, 3), dim3(256), 0, stream,
                       T, Aarr, Barr, Carr);
    hipLaunchKernelGGL(k_roi3, dim3(512), dim3(256), 0, stream,
                       T, Aarr, Barr, Carr, boxes, flat);
    hipLaunchKernelGGL(k_fcm, dim3(32), dim3(256), 0, stream, flat, w1c, cst, flag,
                       d_out);
  } else {
    hipLaunchKernelGGL(k_conv1m, dim3(24, 48), dim3(256), 0, stream,
                       img, flag, A1, cst, feat1);
    for (int c0 = 0; c0 < 64; c0 += cn) {
      hipLaunchKernelGGL(k_conv2_c16, dim3(6, 768), dim3(256), 0, stream,
                         feat1, A2, cst, T, c0, cn);
      hipLaunchKernelGGL(k_csy, dim3(cn*3), dim3(256), 0, stream, T);
      hipLaunchKernelGGL(k_csx, dim3(cn*192), dim3(256), 0, stream, T);
      hipLaunchKernelGGL(k_roi, dim3(512), dim3(256), 0, stream, T, boxes, flat, c0, cn);
    }
    hipLaunchKernelGGL(k_fcm, dim3(32), dim3(256), 0, stream, flat, w1c, cst, flag,
                       d_out);
  }
}

// Round 17
// 201.756 us; speedup vs baseline: 2.6857x; 1.0237x over previous
//
#include <hip/hip_runtime.h>
#include <hip/hip_bf16.h>

#define HH 768
#define WW 768
#define HWSZ (HH*WW)
#define BN_EPS 1e-5f
#define SEG 8            // conv2 y-band height (power of 2: icorner uses >>3)
#define NSEG 96          // 768 / SEG

typedef __attribute__((ext_vector_type(8))) short bf16x8;
typedef __attribute__((ext_vector_type(4))) float f32x4;

__device__ __forceinline__ float bf2f(unsigned short u) {
  union { unsigned int i; float f; } v; v.i = ((unsigned int)u) << 16; return v.f;
}
__device__ __forceinline__ unsigned short f2bf(float f) {
  union { float f; unsigned int i; } v; v.f = f;
  unsigned int x = v.i;
  return (unsigned short)((x + 0x7fffu + ((x >> 16) & 1u)) >> 16);
}
__device__ __forceinline__ float ldf(const void* p, int i, int flag) {
  return flag ? bf2f(((const unsigned short*)p)[i]) : ((const float*)p)[i];
}

// DPP inclusive prefix over each 16-lane row (pure VALU).
#define DPP_ADD(v, CTRL) do {                                              \
    union { float f; int i; } _u; _u.f = (v);                              \
    int _t = __builtin_amdgcn_update_dpp(0, _u.i, (CTRL), 0xf, 0xf, true); \
    union { int i; float f; } _w; _w.i = _t;                               \
    (v) += _w.f;                                                           \
  } while (0)
__device__ __forceinline__ float row_prefix16(float v) {
  DPP_ADD(v, 0x111);
  DPP_ADD(v, 0x112);
  DPP_ADD(v, 0x114);
  DPP_ADD(v, 0x118);
  return v;
}

__device__ __forceinline__ int detect_flag(const void* v1) {
  const unsigned short* v1raw = (const unsigned short*)v1;
  int ok = 1;
  #pragma unroll
  for (int j = 0; j < 4; ++j) {
    unsigned short u = v1raw[2*j];
    if (u < 0x3E00u || u > 0x4040u) ok = 0;
  }
  return ok;   // 1 = bf16 inputs, 0 = fp32 inputs
}

// ---------------- mega-prep + row-owned mask build (grid 256+768) ----------------
// bid <  256 : flag + BN fold + weight reorders (as round 16)
// bid >= 256 : y = bid-256; scan all boxes, build mask row y, write EXCLUSIVELY
__global__ void k_prep(const void* __restrict__ c1b,
                       const void* __restrict__ g1, const void* __restrict__ b1,
                       const void* __restrict__ m1, const void* __restrict__ v1,
                       const void* __restrict__ c2b, const void* __restrict__ g2,
                       const void* __restrict__ b2, const void* __restrict__ m2,
                       const void* __restrict__ v2, const void* __restrict__ w1,
                       const void* __restrict__ fb1, const void* __restrict__ fw2,
                       const void* __restrict__ fb2, const void* __restrict__ w2,
                       const void* __restrict__ fw1, const int* __restrict__ boxes,
                       int* __restrict__ flagp, float* __restrict__ cst,
                       unsigned short* __restrict__ A2, unsigned short* __restrict__ A1,
                       unsigned short* __restrict__ w1c, unsigned int* __restrict__ mask)
{
  int tid = threadIdx.x, bid = blockIdx.x;

  if (bid >= 256) {
    // ---- mask row builder: this block exclusively owns row y ----
    __shared__ unsigned int rowmask[24];
    int y = bid - 256;
    if (tid < 24) rowmask[tid] = 0u;
    __syncthreads();
    for (int b = tid; b < 512; b += 256) {
      int xmin = boxes[b*4 + 0], ymin = boxes[b*4 + 1];
      int xmax = boxes[b*4 + 2], ymax = boxes[b*4 + 3];
      int bh = ymax - ymin, bw = xmax - xmin;
      int hit = 0;
      #pragma unroll
      for (int a = 0; a < 10; ++a) {
        int yc = (a < 5) ? (ymin + ((a+1)*bh + 4)/5 - 1)
                         : (ymin + ((a-5)*bh)/5 - 1);
        if (yc == y) hit = 1;
      }
      if (hit) {
        #pragma unroll
        for (int cix = 0; cix < 10; ++cix) {
          int x = (cix < 5) ? (xmin + ((cix+1)*bw + 4)/5 - 1)
                            : (xmin + ((cix-5)*bw)/5 - 1);
          if (x >= 0) atomicOr(&rowmask[x >> 5], 1u << (x & 31));
        }
      }
    }
    __syncthreads();
    if (tid < 24) mask[y*24 + tid] = rowmask[tid];
    return;
  }

  int flag = detect_flag(v1);
  int gid = bid * 256 + tid;

  if (bid == 0) {
    if (tid == 0) *flagp = flag;
    float* bias1 = cst + 864;
    float* sc1   = cst + 896;
    float* sh1   = cst + 928;
    float* bias2 = cst + 960;
    float* sc2   = cst + 1024;
    float* sh2   = cst + 1088;
    float* fb1c  = cst + 1152;
    float* w2c   = cst + 1280;
    float* fb2c  = cst + 1792;
    if (tid < 32) {
      float s = ldf(g1, tid, flag) * rsqrtf(ldf(v1, tid, flag) + BN_EPS);
      sc1[tid] = s;
      sh1[tid] = ldf(b1, tid, flag) - ldf(m1, tid, flag) * s;
      bias1[tid] = ldf(c1b, tid, flag);
    }
    if (tid < 64) {
      float s = ldf(g2, tid, flag) * rsqrtf(ldf(v2, tid, flag) + BN_EPS);
      sc2[tid] = s;
      sh2[tid] = ldf(b2, tid, flag) - ldf(m2, tid, flag) * s;
      bias2[tid] = ldf(c2b, tid, flag);
    }
    if (tid < 128) fb1c[tid] = ldf(fb1, tid, flag);
    if (tid < 4)   fb2c[tid] = ldf(fb2, tid, flag);
    for (int i = tid; i < 512; i += 256) w2c[i] = ldf(fw2, i, flag);
  }
  if (gid < 80*288) {
    int o = gid / 288, k = gid % 288, tap = k >> 5, ci = k & 31;
    A2[gid] = (o < 64) ? f2bf(ldf(w2, (o*32 + ci)*9 + tap, flag)) : (unsigned short)0;
  }
  if (gid < 32*64) {
    int o = gid >> 6, k = gid & 63, tap = k >> 2, ci = k & 3;
    A1[gid] = (tap < 9 && ci < 3) ? f2bf(ldf(w1, o*27 + ci*9 + tap, flag))
                                  : (unsigned short)0;
  }
  // fc1_w -> bf16 permuted: coalesced reads, scattered writes
  for (int s = gid; s < 128*1600; s += 256*256) {
    int t = s / 1600, r = s % 1600, c = r / 25, cell = r % 25;
    w1c[t*1600 + cell*64 + c] = f2bf(ldf(fw1, s, flag));
  }
}

// ---------------- FUSED conv1+conv2+bn+tile-integral -> T NHWC (sparse stores) ----------------
__global__ __launch_bounds__(256) void k_conv12t(const void* __restrict__ img,
    const int* __restrict__ flagp, const unsigned short* __restrict__ A1,
    const unsigned short* __restrict__ A2, const float* __restrict__ cst,
    const unsigned int* __restrict__ mask, float* __restrict__ T)
{
  const float* bias1 = cst + 864;
  const float* sc1   = cst + 896;
  const float* sh1   = cst + 928;
  const float* bias2 = cst + 960;
  const float* sc2   = cst + 1024;
  const float* sh2   = cst + 1088;
  __shared__ unsigned short ftile[10 * 34 * 40];   // feat1 tile, 27,200 B
  __shared__ unsigned short itile[12 * 36 * 4];    // img tile,    3,456 B
  int flag = *flagp;
  int tid = threadIdx.x;
  int xb = blockIdx.x, ys = blockIdx.y;
  int x0 = xb * 32, ybase = ys * SEG;

  // preload the 8 mask words (block-uniform addresses -> s_loads, latency
  // hidden behind staging; removes a dependent global load from the epilogue)
  unsigned int mwv[SEG];
  #pragma unroll
  for (int dy = 0; dy < SEG; ++dy) mwv[dy] = mask[(ybase + dy)*24 + xb];

  for (int idx = tid; idx < 12*36; idx += 256) {
    int r = idx / 36, p = idx % 36;
    int gy = ybase - 2 + r, gx = x0 - 2 + p;
    unsigned short e0 = 0, e1 = 0, e2 = 0;
    if (gy >= 0 && gy < HH && gx >= 0 && gx < WW) {
      e0 = f2bf(ldf(img, 0*HWSZ + gy*WW + gx, flag));
      e1 = f2bf(ldf(img, 1*HWSZ + gy*WW + gx, flag));
      e2 = f2bf(ldf(img, 2*HWSZ + gy*WW + gx, flag));
    }
    ushort4 pk; pk.x = e0; pk.y = e1; pk.z = e2; pk.w = 0;
    *(ushort4*)(itile + idx*4) = pk;
  }

  int w = tid >> 6, lane = tid & 63, quad = lane >> 4, l16 = lane & 15;

  bf16x8 a1f[2][2];
  #pragma unroll
  for (int mt = 0; mt < 2; ++mt)
    #pragma unroll
    for (int kt = 0; kt < 2; ++kt)
      a1f[mt][kt] = *(const bf16x8*)(A1 + (mt*16 + l16)*64 + kt*32 + quad*8);
  int t0 = 2*quad, t1 = 2*quad + 1;
  int ky0 = t0/3, kx0 = t0%3, ky1 = t1/3, kx1 = t1%3;

  int m = w * 16 + l16;
  bf16x8 afrag[9];
  #pragma unroll
  for (int t = 0; t < 9; ++t)
    afrag[t] = *(const bf16x8*)(A2 + m*288 + t*32 + quad*8);
  float bs[4], scv[4], shv[4];
  #pragma unroll
  for (int r = 0; r < 4; ++r) {
    int c = w*16 + quad*4 + r;
    bs[r] = bias2[c]; scv[r] = sc2[c]; shv[r] = sh2[c];
  }
  __syncthreads();   // itile staged

  for (int u = w; u < 30; u += 4) {
    int r = u / 3, nt = u % 3;
    int pxb = nt*16 + l16;
    int pp = (pxb <= 33) ? pxb : 33;
    union { uint2 q[2]; bf16x8 v; } b0;
    b0.q[0] = *(const uint2*)(itile + ((r + ky0)*36 + pp + kx0)*4);
    b0.q[1] = *(const uint2*)(itile + ((r + ky1)*36 + pp + kx1)*4);
    union { uint2 q[2]; bf16x8 v; } b1v;
    b1v.q[0] = *(const uint2*)(itile + ((r + 2)*36 + pp + 2)*4);
    b1v.q[1] = make_uint2(0u, 0u);
    f32x4 acc[2];
    acc[0] = (f32x4){0.f,0.f,0.f,0.f};
    acc[1] = (f32x4){0.f,0.f,0.f,0.f};
    #pragma unroll
    for (int mt = 0; mt < 2; ++mt) {
      acc[mt] = __builtin_amdgcn_mfma_f32_16x16x32_bf16(a1f[mt][0], b0.v, acc[mt], 0, 0, 0);
      acc[mt] = __builtin_amdgcn_mfma_f32_16x16x32_bf16(a1f[mt][1], b1v.v, acc[mt], 0, 0, 0);
    }
    int py = ybase - 1 + r, gx = x0 - 1 + pxb;
    int inside = (py >= 0 && py < HH && gx >= 0 && gx < WW);
    if (pxb < 34) {
      #pragma unroll
      for (int mt = 0; mt < 2; ++mt) {
        int cb = mt*16 + quad*4;
        ushort4 pk;
        if (inside) {
          pk.x = f2bf(fmaxf(acc[mt][0] + bias1[cb+0], 0.f) * sc1[cb+0] + sh1[cb+0]);
          pk.y = f2bf(fmaxf(acc[mt][1] + bias1[cb+1], 0.f) * sc1[cb+1] + sh1[cb+1]);
          pk.z = f2bf(fmaxf(acc[mt][2] + bias1[cb+2], 0.f) * sc1[cb+2] + sh1[cb+2]);
          pk.w = f2bf(fmaxf(acc[mt][3] + bias1[cb+3], 0.f) * sc1[cb+3] + sh1[cb+3]);
        } else {
          pk.x = pk.y = pk.z = pk.w = 0;
        }
        *(ushort4*)(ftile + (r*34 + pxb)*40 + cb) = pk;
      }
    }
  }
  __syncthreads();   // ftile complete; read-only afterwards

  f32x4 ys0 = (f32x4){0.f,0.f,0.f,0.f};
  f32x4 ys1 = (f32x4){0.f,0.f,0.f,0.f};
  int cbase = w*16 + quad*4;
  for (int dy = 0; dy < SEG; ++dy) {
    int y = ybase + dy;
    f32x4 acc[2];
    acc[0] = (f32x4){0.f,0.f,0.f,0.f};
    acc[1] = (f32x4){0.f,0.f,0.f,0.f};
    #pragma unroll
    for (int t = 0; t < 9; ++t) {
      int ky = t / 3, kx = t % 3;
      #pragma unroll
      for (int i = 0; i < 2; ++i) {
        int px = i*16 + l16 + kx;
        bf16x8 b = *(const bf16x8*)(ftile + ((dy + ky)*34 + px)*40 + quad*8);
        acc[i] = __builtin_amdgcn_mfma_f32_16x16x32_bf16(afrag[t], b, acc[i], 0, 0, 0);
      }
    }
    #pragma unroll
    for (int r = 0; r < 4; ++r) {
      float v0 = fmaxf(acc[0][r] + bs[r], 0.f) * scv[r] + shv[r];
      float v1 = fmaxf(acc[1][r] + bs[r], 0.f) * scv[r] + shv[r];
      v0 = row_prefix16(v0);
      v1 = row_prefix16(v1);
      v1 += __shfl(v0, 15, 16);
      ys0[r] += v0;
      ys1[r] += v1;
    }
    unsigned int mw = mwv[dy];
    int need0 = (dy == SEG-1) || ((mw >> l16) & 1u);
    int need1 = (dy == SEG-1) || (l16 == 15) || ((mw >> (16 + l16)) & 1u);
    if (need0)
      *(f32x4*)(T + ((size_t)(y*WW + x0 + l16))*64 + cbase)      = ys0;
    if (need1)
      *(f32x4*)(T + ((size_t)(y*WW + x0 + 16 + l16))*64 + cbase) = ys1;
  }
}

// ---------------- k_abc: A, B (plain), C — all from T, one launch ----------------
__global__ __launch_bounds__(256) void k_abc(const float* __restrict__ T,
    float* __restrict__ A, float* __restrict__ B, float* __restrict__ C)
{
  __shared__ float gtot[4][64];
  __shared__ float Sp[NSEG*24];
  int part = blockIdx.y, tid = threadIdx.x;
  int c = tid & 63, g = tid >> 6;
  if (part == 0) {
    int y = blockIdx.x;
    float vals[6];
    float run = 0.f;
    #pragma unroll
    for (int jj = 0; jj < 6; ++jj) {
      int j = g*6 + jj;
      run += T[((size_t)(y*WW + j*32 + 31))*64 + c];
      vals[jj] = run;
    }
    gtot[g][c] = run;
    __syncthreads();
    float off = 0.f;
    for (int gg = 0; gg < g; ++gg) off += gtot[gg][c];
    #pragma unroll
    for (int jj = 0; jj < 6; ++jj)
      A[((size_t)(y*24 + g*6 + jj))*64 + c] = vals[jj] + off;
  } else if (part == 1) {
    int x = blockIdx.x;
    float vals[24];
    float run = 0.f;
    #pragma unroll 4
    for (int ii = 0; ii < 24; ++ii) {
      int i = g*24 + ii;
      run += T[((size_t)((i*SEG + SEG-1)*WW + x))*64 + c];
      vals[ii] = run;
    }
    gtot[g][c] = run;
    __syncthreads();
    float off = 0.f;
    for (int gg = 0; gg < g; ++gg) off += gtot[gg][c];
    #pragma unroll 4
    for (int ii = 0; ii < 24; ++ii) {
      int i = g*24 + ii;
      B[((size_t)(i*WW + x))*64 + c] = vals[ii] + off;
    }
  } else {
    int cc = blockIdx.x;
    if (cc >= 64) return;
    for (int idx = tid; idx < NSEG*24; idx += 256) {
      int i = idx / 24, j = idx % 24;
      Sp[idx] = T[((size_t)((i*SEG + SEG-1)*WW + j*32 + 31))*64 + cc];
    }
    __syncthreads();
    if (tid < 24) {              // prefix over i
      float run = 0.f;
      for (int i = 0; i < NSEG; ++i) { run += Sp[i*24 + tid]; Sp[i*24 + tid] = run; }
    }
    __syncthreads();
    if (tid < NSEG) {            // prefix over j
      float run = 0.f;
      #pragma unroll
      for (int j = 0; j < 24; ++j) { run += Sp[tid*24 + j]; Sp[tid*24 + j] = run; }
    }
    __syncthreads();
    for (int idx = tid; idx < NSEG*24; idx += 256)
      C[((size_t)idx)*64 + cc] = Sp[idx];
  }
}

// ---------------- 4-term corner ----------------
__device__ __forceinline__ float icorner4(const float* __restrict__ T,
    const float* __restrict__ A, const float* __restrict__ B,
    const float* __restrict__ C, int c, int yy, int xx)
{
  int i = yy >> 3, j = xx >> 5;      // SEG == 8
  float v = T[((size_t)(yy*WW + xx))*64 + c];
  if (j > 0) v += A[((size_t)(yy*24 + (j-1)))*64 + c];
  if (i > 0) v += B[((size_t)((i-1)*WW + xx))*64 + c];
  if (i > 0 && j > 0) v += C[((size_t)((i-1)*24 + (j-1)))*64 + c];
  return v;
}

// ---------------- ROI pool (512 blocks — full gather TLP) -> flat bf16 ----------------
__global__ __launch_bounds__(256) void k_roi3(const float* __restrict__ T,
    const float* __restrict__ A, const float* __restrict__ B,
    const float* __restrict__ C, const int* __restrict__ boxes,
    unsigned short* __restrict__ flat)
{
  int b = blockIdx.x;
  int xmin = boxes[b*4 + 0], ymin = boxes[b*4 + 1];
  int xmax = boxes[b*4 + 2], ymax = boxes[b*4 + 3];
  int bh = ymax - ymin, bw = xmax - xmin;
  for (int idx = threadIdx.x; idx < 1600; idx += 256) {
    int c = idx & 63, cell = idx >> 6, i = cell / 5, j = cell % 5;
    int y0 = ymin + (i*bh)/5,  y1 = ymin + ((i+1)*bh + 4)/5;
    int x0 = xmin + (j*bw)/5,  x1 = xmin + ((j+1)*bw + 4)/5;
    float s = icorner4(T, A, B, C, c, y1-1, x1-1);
    if (y0 > 0)           s -= icorner4(T, A, B, C, c, y0-1, x1-1);
    if (x0 > 0)           s -= icorner4(T, A, B, C, c, y1-1, x0-1);
    if (y0 > 0 && x0 > 0) s += icorner4(T, A, B, C, c, y0-1, x0-1);
    float area = (float)((y1 - y0) * (x1 - x0));
    flat[b*1600 + cell*64 + c] = f2bf(s / area);
  }
}

// ---------------- FC1 (MFMA) + relu + FC2, 16 boxes/block ----------------
__global__ __launch_bounds__(256) void k_fcm(const unsigned short* __restrict__ flat,
    const unsigned short* __restrict__ w1c, const float* __restrict__ cst,
    const int* __restrict__ flagp, void* __restrict__ out)
{
  const float* fb1c = cst + 1152;
  const float* w2c  = cst + 1280;
  const float* fb2c = cst + 1792;
  __shared__ unsigned short sflat[16 * 1608];
  __shared__ float hbuf[16 * 132];
  int tid = threadIdx.x;
  int b0 = blockIdx.x * 16;
  for (int ii = tid; ii < 3200; ii += 256) {
    int bi = ii / 200, ch = ii % 200;
    *(uint4*)(sflat + bi*1608 + ch*8) = *(const uint4*)(flat + (b0 + bi)*1600 + ch*8);
  }
  __syncthreads();
  int w = tid >> 6, lane = tid & 63, quad = lane >> 4, l16 = lane & 15;
  f32x4 acc[2];
  acc[0] = (f32x4){0.f,0.f,0.f,0.f};
  acc[1] = (f32x4){0.f,0.f,0.f,0.f};
  for (int kt = 0; kt < 50; ++kt) {
    bf16x8 b = *(const bf16x8*)(sflat + l16*1608 + kt*32 + quad*8);
    #pragma unroll
    for (int mt = 0; mt < 2; ++mt) {
      bf16x8 a = *(const bf16x8*)(w1c + ((w*2 + mt)*16 + l16)*1600 + kt*32 + quad*8);
      acc[mt] = __builtin_amdgcn_mfma_f32_16x16x32_bf16(a, b, acc[mt], 0, 0, 0);
    }
  }
  #pragma unroll
  for (int mt = 0; mt < 2; ++mt) {
    #pragma unroll
    for (int r = 0; r < 4; ++r) {
      int h = (w*2 + mt)*16 + quad*4 + r;
      hbuf[l16*132 + h] = fmaxf(acc[mt][r] + fb1c[h], 0.f);
    }
  }
  __syncthreads();
  if (tid < 64) {
    int bi = tid >> 2, o = tid & 3;
    float a2 = fb2c[o];
    for (int k = 0; k < 128; ++k) a2 += hbuf[bi*132 + k] * w2c[o*128 + k];
    if (*flagp) ((unsigned short*)out)[(b0 + bi)*4 + o] = f2bf(a2);
    else        ((float*)out)[(b0 + bi)*4 + o] = a2;
  }
}

// ---------------- fallback path (chunked CHW, proven) ----------------
__global__ __launch_bounds__(256) void k_conv1m(const void* __restrict__ img,
    const int* __restrict__ flagp, const unsigned short* __restrict__ A1,
    const float* __restrict__ cst, unsigned short* __restrict__ feat1)
{
  const float* bias1 = cst + 864;
  const float* sc1   = cst + 896;
  const float* sh1   = cst + 928;
  int flag = *flagp;
  __shared__ unsigned short tile[18 * 34 * 4];
  int tid = threadIdx.x;
  int x0 = blockIdx.x * 32, ybase = blockIdx.y * 16;
  for (int idx = tid; idx < 18*34; idx += 256) {
    int r = idx / 34, p = idx % 34;
    int gy = ybase - 1 + r, gx = x0 - 1 + p;
    unsigned short e0 = 0, e1 = 0, e2 = 0;
    if (gy >= 0 && gy < HH && gx >= 0 && gx < WW) {
      e0 = f2bf(ldf(img, 0*HWSZ + gy*WW + gx, flag));
      e1 = f2bf(ldf(img, 1*HWSZ + gy*WW + gx, flag));
      e2 = f2bf(ldf(img, 2*HWSZ + gy*WW + gx, flag));
    }
    ushort4 pk; pk.x = e0; pk.y = e1; pk.z = e2; pk.w = 0;
    *(ushort4*)(tile + idx*4) = pk;
  }
  int w = tid >> 6, lane = tid & 63, quad = lane >> 4, l16 = lane & 15;
  bf16x8 a1f[2][2];
  #pragma unroll
  for (int mt = 0; mt < 2; ++mt)
    #pragma unroll
    for (int kt = 0; kt < 2; ++kt)
      a1f[mt][kt] = *(const bf16x8*)(A1 + (mt*16 + l16)*64 + kt*32 + quad*8);
  int t0 = 2*quad, t1 = 2*quad + 1;
  int ky0 = t0/3, kx0 = t0%3, ky1 = t1/3, kx1 = t1%3;
  __syncthreads();
  for (int dyw = 0; dyw < 4; ++dyw) {
    int dy = dyw*4 + w;
    int y = ybase + dy;
    f32x4 acc[2][2];
    #pragma unroll
    for (int mt = 0; mt < 2; ++mt)
      #pragma unroll
      for (int i = 0; i < 2; ++i)
        acc[mt][i] = (f32x4){0.f,0.f,0.f,0.f};
    #pragma unroll
    for (int i = 0; i < 2; ++i) {
      int pxb = i*16 + l16;
      union { uint2 q[2]; bf16x8 v; } b0;
      b0.q[0] = *(const uint2*)(tile + ((dy + ky0)*34 + pxb + kx0)*4);
      b0.q[1] = *(const uint2*)(tile + ((dy + ky1)*34 + pxb + kx1)*4);
      union { uint2 q[2]; bf16x8 v; } b1v;
      b1v.q[0] = *(const uint2*)(tile + ((dy + 2)*34 + pxb + 2)*4);
      b1v.q[1] = make_uint2(0u, 0u);
      #pragma unroll
      for (int mt = 0; mt < 2; ++mt) {
        acc[mt][i] = __builtin_amdgcn_mfma_f32_16x16x32_bf16(a1f[mt][0], b0.v, acc[mt][i], 0, 0, 0);
        acc[mt][i] = __builtin_amdgcn_mfma_f32_16x16x32_bf16(a1f[mt][1], b1v.v, acc[mt][i], 0, 0, 0);
      }
    }
    #pragma unroll
    for (int mt = 0; mt < 2; ++mt) {
      int cb = mt*16 + quad*4;
      #pragma unroll
      for (int i = 0; i < 2; ++i) {
        int px = x0 + i*16 + l16;
        ushort4 pk;
        pk.x = f2bf(fmaxf(acc[mt][i][0] + bias1[cb+0], 0.f) * sc1[cb+0] + sh1[cb+0]);
        pk.y = f2bf(fmaxf(acc[mt][i][1] + bias1[cb+1], 0.f) * sc1[cb+1] + sh1[cb+1]);
        pk.z = f2bf(fmaxf(acc[mt][i][2] + bias1[cb+2], 0.f) * sc1[cb+2] + sh1[cb+2]);
        pk.w = f2bf(fmaxf(acc[mt][i][3] + bias1[cb+3], 0.f) * sc1[cb+3] + sh1[cb+3]);
        *(ushort4*)(feat1 + ((size_t)(y*WW + px))*32 + cb) = pk;
      }
    }
  }
}
__global__ __launch_bounds__(256) void k_conv2_c16(const unsigned short* __restrict__ feat1,
    const unsigned short* __restrict__ A2, const float* __restrict__ cst,
    float* __restrict__ chunk, int c0, int cnw)
{
  const float* bias2 = cst + 960;
  const float* sc2   = cst + 1024;
  const float* sh2   = cst + 1088;
  __shared__ unsigned short tile[3 * 130 * 40];
  int tid = threadIdx.x;
  int y = blockIdx.y, x0 = blockIdx.x * 128;
  for (int idx = tid; idx < 3*130*4; idx += 256) {
    int q = idx & 3, p = (idx >> 2) % 130, r = idx / 520;
    int gy = y - 1 + r, gx = x0 - 1 + p;
    uint4 val = make_uint4(0u, 0u, 0u, 0u);
    if (gy >= 0 && gy < HH && gx >= 0 && gx < WW)
      val = *(const uint4*)(feat1 + (gy*WW + gx)*32 + q*8);
    *(uint4*)(tile + (r*130 + p)*40 + q*8) = val;
  }
  __syncthreads();
  int w = tid >> 6, lane = tid & 63, quad = lane >> 4, l16 = lane & 15;
  int m = c0 + l16;
  f32x4 acc[2];
  acc[0] = (f32x4){0.f,0.f,0.f,0.f};
  acc[1] = (f32x4){0.f,0.f,0.f,0.f};
  #pragma unroll
  for (int t = 0; t < 9; ++t) {
    int ky = t / 3, kx = t % 3;
    bf16x8 a = *(const bf16x8*)(A2 + m*288 + t*32 + quad*8);
    #pragma unroll
    for (int i = 0; i < 2; ++i) {
      int px = w*32 + i*16 + l16 + kx;
      bf16x8 b = *(const bf16x8*)(tile + (ky*130 + px)*40 + quad*8);
      acc[i] = __builtin_amdgcn_mfma_f32_16x16x32_bf16(a, b, acc[i], 0, 0, 0);
    }
  }
  #pragma unroll
  for (int r = 0; r < 4; ++r) {
    int cl = quad*4 + r;
    if (cl < cnw) {
      int c = c0 + cl;
      float bsv = bias2[c], s = sc2[c], sh = sh2[c];
      float* dst = chunk + cl*HWSZ + y*WW;
      #pragma unroll
      for (int i = 0; i < 2; ++i) {
        float v = fmaxf(acc[i][r] + bsv, 0.f) * s + sh;
        dst[x0 + w*32 + i*16 + l16] = v;
      }
    }
  }
}
__global__ __launch_bounds__(256) void k_csy(float* __restrict__ buf) {
  int t = blockIdx.x * 256 + threadIdx.x;
  int c = t / WW, x = t % WW;
  float* p = buf + c*HWSZ + x;
  float run = 0.f;
  for (int yb = 0; yb < HH; yb += 16) {
    float v[16];
    #pragma unroll
    for (int j = 0; j < 16; ++j) v[j] = p[(yb + j) * WW];
    #pragma unroll
    for (int j = 0; j < 16; ++j) { run += v[j]; v[j] = run; }
    #pragma unroll
    for (int j = 0; j < 16; ++j) p[(yb + j) * WW] = v[j];
  }
}
__global__ __launch_bounds__(256) void k_csx(float* __restrict__ buf) {
  int row = blockIdx.x * 4 + (threadIdx.x >> 6);
  int lane = threadIdx.x & 63;
  float* p = buf + (long)row * WW;
  float carry = 0.f;
  for (int ch = 0; ch < 12; ++ch) {
    float v = p[ch*64 + lane];
    #pragma unroll
    for (int off = 1; off < 64; off <<= 1) {
      float t = __shfl_up(v, off);
      v = (lane >= off) ? v + t : v;
    }
    v += carry;
    p[ch*64 + lane] = v;
    carry = __shfl(v, 63);
  }
}
__global__ __launch_bounds__(256) void k_roi(const float* __restrict__ integ,
    const int* __restrict__ boxes, unsigned short* __restrict__ flat, int c0, int cn)
{
  int b = blockIdx.x;
  int xmin = boxes[b*4 + 0], ymin = boxes[b*4 + 1];
  int xmax = boxes[b*4 + 2], ymax = boxes[b*4 + 3];
  int bh = ymax - ymin, bw = xmax - xmin;
  for (int idx = threadIdx.x; idx < cn*25; idx += 256) {
    int cl = idx / 25, cell = idx % 25, i = cell / 5, j = cell % 5;
    int y0 = ymin + (i*bh)/5,      y1 = ymin + ((i+1)*bh + 4)/5;
    int x0 = xmin + (j*bw)/5,      x1 = xmin + ((j+1)*bw + 4)/5;
    const float* I = integ + cl*HWSZ;
    float a  = I[(y1-1)*WW + (x1-1)];
    float bl = (y0 > 0) ? I[(y0-1)*WW + (x1-1)] : 0.f;
    float cr = (x0 > 0) ? I[(y1-1)*WW + (x0-1)] : 0.f;
    float d  = (y0 > 0 && x0 > 0) ? I[(y0-1)*WW + (x0-1)] : 0.f;
    float s = a - bl - cr + d;
    float area = (float)((y1 - y0) * (x1 - x0));
    flat[b*1600 + cell*64 + (c0 + cl)] = f2bf(s / area);
  }
}

extern "C" void kernel_launch(void* const* d_in, const int* in_sizes, int n_in,
                              void* d_out, int out_size, void* d_ws, size_t ws_size,
                              hipStream_t stream) {
  const void* img = d_in[0];
  const int* boxes = (const int*)d_in[1];
  const void* c1w = d_in[2];  const void* c1b = d_in[3];
  const void* g1  = d_in[4];  const void* b1  = d_in[5];
  const void* m1  = d_in[6];  const void* v1  = d_in[7];
  const void* c2w = d_in[8];  const void* c2b = d_in[9];
  const void* g2  = d_in[10]; const void* b2  = d_in[11];
  const void* m2  = d_in[12]; const void* v2  = d_in[13];
  const void* fw1 = d_in[14]; const void* fb1 = d_in[15];
  const void* fw2 = d_in[16]; const void* fb2 = d_in[17];

  // ws layout (same offsets as rounds 13-16):
  char* ws = (char*)d_ws;
  unsigned short* A2 = (unsigned short*)ws;
  unsigned short* A1 = (unsigned short*)(ws + 46080);
  float* cst = (float*)(ws + 50176);
  int* flag = (int*)(ws + 57360);
  unsigned int* mask = (unsigned int*)(ws + 57376);
  unsigned short* w1c  = (unsigned short*)(ws + 3592224);
  unsigned short* flat = (unsigned short*)(ws + 4001824);
  unsigned short* feat1 = (unsigned short*)(ws + 7278624);  // fallback only
  float* T = (float*)(ws + 45027360);
  float* Aarr = (float*)(ws + 7278624);
  float* Barr = Aarr + (size_t)768*24*64;
  float* Carr = Barr + (size_t)NSEG*768*64;

  const size_t base = 45027360;
  int cn;
  if      (ws_size >= base + 64ull*HWSZ*4) cn = 64;
  else if (ws_size >= base + 16ull*HWSZ*4) cn = 16;
  else if (ws_size >= base +  8ull*HWSZ*4) cn = 8;
  else if (ws_size >= base +  4ull*HWSZ*4) cn = 4;
  else if (ws_size >= base +  2ull*HWSZ*4) cn = 2;
  else                                     cn = 1;

  hipLaunchKernelGGL(k_prep, dim3(1024), dim3(256), 0, stream,
                     c1b, g1, b1, m1, v1, c2b, g2, b2, m2, v2, c1w,
                     fb1, fw2, fb2, c2w, fw1, boxes, flag, cst, A2, A1, w1c, mask);

  if (cn == 64) {
    hipLaunchKernelGGL(k_conv12t, dim3(24, NSEG), dim3(256), 0, stream,
                       img, flag, A1, A2, cst, mask, T);
    hipLaunchKernelGGL(k_abc, dim3(768, 3), dim3(256), 0, stream,
                       T, Aarr, Barr, Carr);
    hipLaunchKernelGGL(k_roi3, dim3(512), dim3(256), 0, stream,
                       T, Aarr, Barr, Carr, boxes, flat);
    hipLaunchKernelGGL(k_fcm, dim3(32), dim3(256), 0, stream, flat, w1c, cst, flag,
                       d_out);
  } else {
    hipLaunchKernelGGL(k_conv1m, dim3(24, 48), dim3(256), 0, stream,
                       img, flag, A1, cst, feat1);
    for (int c0 = 0; c0 < 64; c0 += cn) {
      hipLaunchKernelGGL(k_conv2_c16, dim3(6, 768), dim3(256), 0, stream,
                         feat1, A2, cst, T, c0, cn);
      hipLaunchKernelGGL(k_csy, dim3(cn*3), dim3(256), 0, stream, T);
      hipLaunchKernelGGL(k_csx, dim3(cn*192), dim3(256), 0, stream, T);
      hipLaunchKernelGGL(k_roi, dim3(512), dim3(256), 0, stream, T, boxes, flat, c0, cn);
    }
    hipLaunchKernelGGL(k_fcm, dim3(32), dim3(256), 0, stream, flat, w1c, cst, flag,
                       d_out);
  }
}